// Round 7
// baseline (407.483 us; speedup 1.0000x reference)
//
#include <hip/hip_runtime.h>
#include <hip/hip_bf16.h>

// ---------------------------------------------------------------------------
// TernaryCIFAR10Net on MI355X — Round 7:
//   conv2/conv3 -> int8 MFMA (mfma_i32_16x16x64_i8, 2x bf16 rate), exact
//   15-bit fixed-point activations (q = qh*256+ql, both i8), runtime amax
//   scales via producer-epilogue atomicMax. Halves K-loop MFMA cycles, LDS
//   traffic and LDS footprint vs bf16 hi/lo.
//   conv1 (fp32 direct), fc1 (bf16 MFMA split-K), fc2, ternarize unchanged.
// Inter-layer activation format: per pixel row = [hi x C][lo x C] bf16.
// ---------------------------------------------------------------------------

typedef __attribute__((ext_vector_type(8))) short short8;
typedef __attribute__((ext_vector_type(4))) float f32x4;
typedef __attribute__((ext_vector_type(4))) int i32x4;

__device__ __forceinline__ unsigned short f2bf(float x) {
    unsigned u = __float_as_uint(x);
    return (unsigned short)((u + 0x7fffu + ((u >> 16) & 1u)) >> 16);  // RNE
}
__device__ __forceinline__ float bf2f(unsigned short b) {
    return __uint_as_float(((unsigned)b) << 16);
}

// workspace layout (4-byte units)
#define WS_WT1   0
#define N_WT1    (64*3*3*3)
#define WS_W2P   (WS_WT1 + N_WT1)
#define N_W2P    (9*128*64)            // int8 signs (over-allocated)
#define WS_W3P   (WS_W2P + N_W2P)
#define N_W3P    (9*256*128)
#define WS_WTF1  (WS_W3P + N_W3P)
#define N_WTF1   (256*4096)            // ushort signs [256][8192]
#define WS_WTF2  (WS_WTF1 + N_WTF1)
#define N_WTF2   (10*256)
#define WS_A1    (WS_WTF2 + N_WTF2)
#define N_A1     (1024*256*64)         // a1: [B][256px][128 ushort]; parts alias
#define WS_A2    (WS_A1 + N_A1)
#define N_A2     (1024*64*128)         // a2: [B][64px][256 ushort]
#define WS_A3    (WS_A2 + N_A2)
#define N_A3     (1024*16*256)         // a3: [B][16px][512 ushort]
#define WS_F1    (WS_A3 + N_A3)
#define N_F1     (1024*256)
#define WS_SCR   (WS_F1 + N_F1)

#define FC1_S    16

struct TernArgs {
    const float* w[5];
    int n[5];
};

// ---------------------------------------------------------------------------
// Ternarize stats (fused over 5 weights): scr[wi] = {sum|w|, msum, count, pad}
// ---------------------------------------------------------------------------
__global__ void tern_stats1(TernArgs ta, double* __restrict__ scr) {
    const int wi = blockIdx.y;
    const float* __restrict__ w = ta.w[wi];
    const int n = ta.n[wi];
    double s = 0.0;
    for (int i = blockIdx.x * blockDim.x + threadIdx.x; i < n;
         i += gridDim.x * blockDim.x)
        s += (double)fabsf(w[i]);
    #pragma unroll
    for (int off = 32; off > 0; off >>= 1) s += __shfl_down(s, off, 64);
    __shared__ double red[4];
    const int lane = threadIdx.x & 63, wv = threadIdx.x >> 6;
    if (lane == 0) red[wv] = s;
    __syncthreads();
    if (threadIdx.x == 0)
        atomicAdd(scr + wi * 4, red[0] + red[1] + red[2] + red[3]);
}

__global__ void tern_stats2(TernArgs ta, double* __restrict__ scr) {
    const int wi = blockIdx.y;
    const float* __restrict__ w = ta.w[wi];
    const int n = ta.n[wi];
    const float delta = (float)(0.7 * scr[wi * 4] / (double)n);
    double ms = 0.0, cnt = 0.0;
    for (int i = blockIdx.x * blockDim.x + threadIdx.x; i < n;
         i += gridDim.x * blockDim.x) {
        float a = fabsf(w[i]);
        if (a > delta) { ms += (double)a; cnt += 1.0; }
    }
    #pragma unroll
    for (int off = 32; off > 0; off >>= 1) {
        ms += __shfl_down(ms, off, 64);
        cnt += __shfl_down(cnt, off, 64);
    }
    __shared__ double redm[4], redc[4];
    const int lane = threadIdx.x & 63, wv = threadIdx.x >> 6;
    if (lane == 0) { redm[wv] = ms; redc[wv] = cnt; }
    __syncthreads();
    if (threadIdx.x == 0) {
        atomicAdd(scr + wi * 4 + 1, redm[0] + redm[1] + redm[2] + redm[3]);
        atomicAdd(scr + wi * 4 + 2, redc[0] + redc[1] + redc[2] + redc[3]);
    }
}

// ---------------------------------------------------------------------------
// Fused writer.
//   0: w1  -> wt1 fp32 alpha*sign
//   1: w2  -> w2p8 int8 sign [tap][co][ci]   (CO=128, CI=64)
//   2: w3  -> w3p8 int8 sign                 (CO=256, CI=128)
//   3: wf1 -> wtf1b ushort bf16 sign [j][8192]: k = px*512 + c (hi), +256 (lo)
//   4: wf2 -> wtf2 fp32 alpha*sign
// ---------------------------------------------------------------------------
__global__ void tern_write_all(TernArgs ta, const double* __restrict__ scr,
                               float* __restrict__ wt1,
                               signed char* __restrict__ w2p8,
                               signed char* __restrict__ w3p8,
                               unsigned short* __restrict__ wtf1b,
                               float* __restrict__ wtf2) {
    const int wi = blockIdx.y;
    const float* __restrict__ w = ta.w[wi];
    const int n = ta.n[wi];
    const double* sc = scr + wi * 4;
    const float delta = (float)(0.7 * sc[0] / (double)n);
    const int i0 = blockIdx.x * blockDim.x + threadIdx.x;
    const int stride = gridDim.x * blockDim.x;

    if (wi == 0 || wi == 4) {
        const double c = sc[2];
        const float alpha = (float)(sc[1] / (c > 1.0 ? c : 1.0));
        float* dst = (wi == 0) ? wt1 : wtf2;
        for (int i = i0; i < n; i += stride) {
            float v = w[i];
            dst[i] = (fabsf(v) > delta) ? (v > 0.0f ? alpha : -alpha) : 0.0f;
        }
    } else if (wi == 1 || wi == 2) {
        const int CIc = (wi == 1) ? 64 : 128;
        const int COc = (wi == 1) ? 128 : 256;
        signed char* dst = (wi == 1) ? w2p8 : w3p8;
        for (int i = i0; i < n; i += stride) {
            const int co = i / (CIc * 9);
            const int r = i % (CIc * 9);
            const int ci = r / 9, tap = r % 9;
            float v = w[i];
            signed char s = (fabsf(v) > delta) ? (v > 0.0f ? 1 : -1) : 0;
            dst[(tap * COc + co) * CIc + ci] = s;
        }
    } else {  // wi == 3: fc1 signs, hi and lo slots
        for (int i = i0; i < n; i += stride) {
            const int j = i >> 12;
            const int k = i & 4095;
            const int c = k >> 4, px = k & 15;
            float v = w[i];
            unsigned short s = (fabsf(v) > delta) ? (v > 0.0f ? 0x3f80 : 0xbf80) : 0;
            unsigned short* row = wtf1b + ((long)j << 13) + px * 512 + c;
            row[0] = s;
            row[256] = s;
        }
    }
}

// ---------------------------------------------------------------------------
// conv1: fp32 direct (CI=3), fused bias+relu+pool; output [hi 64][lo 64]
// bf16 per pooled pixel + block amax -> atomicMax (a1 max for conv2's quant).
// ---------------------------------------------------------------------------
__global__ __launch_bounds__(256) void conv1_kernel(
        const float* __restrict__ x, const float* __restrict__ wt,
        const float* __restrict__ bias, unsigned short* __restrict__ y,
        int* __restrict__ amax) {
    constexpr int CI = 3, HI = 32, CO = 64, NCO = 8, PO = 16, NPX = 256;
    const int co0 = blockIdx.y * NCO;
    __shared__ float sw[NCO * CI * 12];
    __shared__ float redm[4];
    for (int i = threadIdx.x; i < NCO * CI * 9; i += 256) {
        const int c = i / (CI * 9);
        const int r = i % (CI * 9);
        const int ci = r / 9, k = r % 9;
        sw[(c * CI + ci) * 12 + k] = wt[((long)(co0 + c) * CI + ci) * 9 + k];
    }
    __syncthreads();

    const int px = threadIdx.x;
    const int b = blockIdx.x;
    const int ph = px / PO, pw = px % PO;
    const int h0 = 2 * ph, w0 = 2 * pw;

    float acc[NCO][4];
    #pragma unroll
    for (int c = 0; c < NCO; c++)
        #pragma unroll
        for (int q = 0; q < 4; q++) acc[c][q] = 0.f;

    const float* xb = x + (long)b * CI * HI * HI;
    for (int ci = 0; ci < CI; ci++) {
        const float* xc = xb + ci * HI * HI;
        float p[4][4];
        #pragma unroll
        for (int r = 0; r < 4; r++) {
            const int h = h0 - 1 + r;
            const bool hin = (unsigned)h < (unsigned)HI;
            #pragma unroll
            for (int c2 = 0; c2 < 4; c2++) {
                const int w = w0 - 1 + c2;
                p[r][c2] = (hin && (unsigned)w < (unsigned)HI) ? xc[h * HI + w] : 0.f;
            }
        }
        #pragma unroll
        for (int c = 0; c < NCO; c++) {
            const float4* w4 = (const float4*)(sw + (c * CI + ci) * 12);
            const float4 wa = w4[0], wb = w4[1], wc = w4[2];
            const float wk[9] = {wa.x, wa.y, wa.z, wa.w, wb.x, wb.y, wb.z, wb.w, wc.x};
            #pragma unroll
            for (int kh = 0; kh < 3; kh++)
                #pragma unroll
                for (int kw = 0; kw < 3; kw++) {
                    const float wvv = wk[kh * 3 + kw];
                    acc[c][0] += wvv * p[kh][kw];
                    acc[c][1] += wvv * p[kh][kw + 1];
                    acc[c][2] += wvv * p[kh + 1][kw];
                    acc[c][3] += wvv * p[kh + 1][kw + 1];
                }
        }
    }
    unsigned short* yr = y + ((long)b * NPX + px) * (2 * CO);
    float tmax = 0.f;
    #pragma unroll
    for (int c = 0; c < NCO; c++) {
        float m = fmaxf(fmaxf(acc[c][0], acc[c][1]), fmaxf(acc[c][2], acc[c][3]));
        float o = fmaxf(m + bias[co0 + c], 0.f);
        tmax = fmaxf(tmax, o);
        unsigned short hi = f2bf(o);
        unsigned short lo = f2bf(o - bf2f(hi));
        yr[co0 + c] = hi;
        yr[CO + co0 + c] = lo;
    }
    // block amax -> atomicMax (positive floats: int compare valid)
    #pragma unroll
    for (int off = 32; off > 0; off >>= 1)
        tmax = fmaxf(tmax, __shfl_down(tmax, off, 64));
    const int lane = threadIdx.x & 63, wv = threadIdx.x >> 6;
    if (lane == 0) redm[wv] = tmax;
    __syncthreads();
    if (threadIdx.x == 0) {
        float m = fmaxf(fmaxf(redm[0], redm[1]), fmaxf(redm[2], redm[3]));
        atomicMax(amax, __float_as_int(m));
    }
}

// ---------------------------------------------------------------------------
// int8 MFMA conv. Input bf16 hi/lo rows; staging quantizes to 15-bit fixed
// point with S = 32512/amax_in and splits q = qh*256+ql (both i8) into two
// LDS planes. K-loop: mfma_i32_16x16x64_i8 per plane (exact integer math),
// 2-stage register pipeline. Epilogue: dq = alpha/S, 2x2 pool register-local.
// A/B share intra-lane k-permutation -> any consistent byte order is correct.
// ---------------------------------------------------------------------------
template <int CI, int HI, int CO, int HB, int NBY>
__global__ __launch_bounds__(256) void conv_i8(
        const unsigned short* __restrict__ xin,
        const signed char* __restrict__ wp,     // [9][CO][CI] int8 signs
        const float* __restrict__ bias,
        const double* __restrict__ scr,         // layer {_, msum, count}
        const int* __restrict__ amax_in,
        int* __restrict__ amax_out,             // nullptr if unused
        unsigned short* __restrict__ yout) {
    constexpr int CH8 = CI / 64;            // K=64 chunks per plane
    constexpr int NITER = 9 * CH8;
    constexpr int HR = HI / HB;
    constexpr int ROWS = HR + 2;
    constexpr int COLS = HI + 2;
    constexpr int NPIX = ROWS * COLS;
    constexpr int PSTR = NPIX * 64 + 32;    // bytes per g-plane
    constexpr int PO = HI / 2;
    constexpr int POR = HR / 2;
    constexpr int MT = 2, NT = 4;

    __shared__ __align__(16) char X[2 * CH8 * PSTR];
    __shared__ float redm[4];

    const int bimg = blockIdx.x / HB;
    const int hb = blockIdx.x % HB;
    const int co0 = (NBY > 1) ? blockIdx.y * 128 : 0;
    const int tid = threadIdx.x;

    const float S = 32512.0f / fmaxf(__int_as_float(*amax_in), 1e-30f);

    // halo zero (borders only; disjoint from interior staging)
    constexpr int HALO = 2 * COLS + 2 * (ROWS - 2);
    for (int i = tid; i < HALO * 2 * CH8 * 4; i += 256) {
        const int u = i & 3;
        const int t = i >> 2;
        const int g = t % (2 * CH8);
        const int hp = t / (2 * CH8);
        int p;
        if (hp < COLS) p = hp;
        else if (hp < 2 * COLS) p = (ROWS - 1) * COLS + (hp - COLS);
        else {
            const int e = hp - 2 * COLS;
            p = (1 + (e >> 1)) * COLS + ((e & 1) ? (COLS - 1) : 0);
        }
        *(int4*)&X[g * PSTR + p * 64 + u * 16] = make_int4(0, 0, 0, 0);
    }

    // interior staging: bf16(hi,lo) -> q -> (ql, qh) planes, slot-swizzled
    for (int i = tid; i < ROWS * HI * (CI / 8); i += 256) {
        const int q8 = i % (CI / 8);
        const int t = i / (CI / 8);
        const int c = t % HI;
        const int r = t / HI;
        const int h = hb * HR + r - 1;
        if ((unsigned)h < (unsigned)HI) {
            const unsigned short* pxr =
                xin + ((long)(bimg * HI + h) * HI + c) * (2 * CI);
            const int c8 = q8 * 8;
            const uint4 vh = *(const uint4*)(pxr + c8);
            const uint4 vl = *(const uint4*)(pxr + CI + c8);
            const unsigned* hw = (const unsigned*)&vh;
            const unsigned* lw = (const unsigned*)&vl;
            unsigned pl0 = 0, pl1 = 0, ph0 = 0, ph1 = 0;
            #pragma unroll
            for (int j = 0; j < 8; j++) {
                const unsigned hu = (j & 1) ? (hw[j >> 1] >> 16)
                                            : (hw[j >> 1] & 0xffffu);
                const unsigned lu = (j & 1) ? (lw[j >> 1] >> 16)
                                            : (lw[j >> 1] & 0xffffu);
                const float f = __uint_as_float(hu << 16) +
                                __uint_as_float(lu << 16);
                const int qi = (int)(f * S + 0.5f);
                const int ql = (qi << 24) >> 24;       // sign-extended low byte
                const int qh = (qi - ql) >> 8;         // in [0,127]
                const int sh = (j & 3) * 8;
                if (j < 4) {
                    pl0 |= (unsigned)(ql & 255) << sh;
                    ph0 |= (unsigned)(qh & 255) << sh;
                } else {
                    pl1 |= (unsigned)(ql & 255) << sh;
                    ph1 |= (unsigned)(qh & 255) << sh;
                }
            }
            const int p = r * COLS + c + 1;
            const int ch = c8 >> 6;
            const int cc = c8 & 63;
            const int slot = ((cc >> 4) + (p >> 1)) & 3;
            const int base = p * 64 + slot * 16 + (cc & 15);
            *(uint2*)&X[ch * PSTR + base] = make_uint2(pl0, pl1);
            *(uint2*)&X[(CH8 + ch) * PSTR + base] = make_uint2(ph0, ph1);
        }
    }
    __syncthreads();

    const int lane = tid & 63;
    const int wid = tid >> 6;
    const int wm = wid >> 1;
    const int wn = wid & 1;
    const int lm = lane & 15;
    const int kg = lane >> 4;

    int pb[MT];
    #pragma unroll
    for (int mt = 0; mt < MT; mt++) {
        const int m = (wm * MT + mt) * 16 + lm;
        const int pp = m >> 2, sub = m & 3;
        const int lph = pp / PO, lpw = pp % PO;
        const int h = 2 * lph + (sub >> 1);
        const int w = 2 * lpw + (sub & 1);
        pb[mt] = h * COLS + w;
    }
    const signed char* bp[NT];
    #pragma unroll
    for (int nt = 0; nt < NT; nt++) {
        const int co = co0 + (wn * NT + nt) * 16 + lm;
        bp[nt] = wp + (long)co * CI + kg * 16;
    }

    i32x4 accL[MT][NT], accH[MT][NT];
    #pragma unroll
    for (int mt = 0; mt < MT; mt++)
        #pragma unroll
        for (int nt = 0; nt < NT; nt++) { accL[mt][nt] = 0; accH[mt][nt] = 0; }

    i32x4 Ab[2][MT][2], Bb[2][NT];
    #pragma unroll
    for (int nt = 0; nt < NT; nt++) Bb[0][nt] = *(const i32x4*)(bp[nt]);
    #pragma unroll
    for (int mt = 0; mt < MT; mt++) {
        const int p = pb[mt];
        const int ao = p * 64 + (((kg + (p >> 1)) & 3) << 4);
        Ab[0][mt][0] = *(const i32x4*)&X[ao];
        Ab[0][mt][1] = *(const i32x4*)&X[CH8 * PSTR + ao];
    }

    #pragma unroll 2
    for (int it = 0; it < NITER; ++it) {
        const int cur = it & 1, nxt = cur ^ 1;
        if (it + 1 < NITER) {
            const int it1 = it + 1;
            const int tap = it1 / CH8, ch = it1 % CH8;
            const int dtap = (tap / 3) * COLS + (tap % 3);
            const int woff = tap * CO * CI + ch * 64;
            #pragma unroll
            for (int nt = 0; nt < NT; nt++)
                Bb[nxt][nt] = *(const i32x4*)(bp[nt] + woff);
            #pragma unroll
            for (int mt = 0; mt < MT; mt++) {
                const int p = pb[mt] + dtap;
                const int ao = p * 64 + (((kg + (p >> 1)) & 3) << 4);
                Ab[nxt][mt][0] = *(const i32x4*)&X[ch * PSTR + ao];
                Ab[nxt][mt][1] = *(const i32x4*)&X[(CH8 + ch) * PSTR + ao];
            }
        }
        #pragma unroll
        for (int mt = 0; mt < MT; mt++)
            #pragma unroll
            for (int nt = 0; nt < NT; nt++) {
                accL[mt][nt] = __builtin_amdgcn_mfma_i32_16x16x64_i8(
                    Ab[cur][mt][0], Bb[cur][nt], accL[mt][nt], 0, 0, 0);
                accH[mt][nt] = __builtin_amdgcn_mfma_i32_16x16x64_i8(
                    Ab[cur][mt][1], Bb[cur][nt], accH[mt][nt], 0, 0, 0);
            }
    }

    // epilogue: sum = 256*accH + accL (exact i32); pool = int max (dq >= 0)
    const double c2 = scr[2];
    const float alpha = (float)(scr[1] / (c2 > 1.0 ? c2 : 1.0));
    const float dq = alpha / S;
    float tmax = 0.f;
    #pragma unroll
    for (int mt = 0; mt < MT; mt++) {
        const int pp = (wm * MT + mt) * 4 + kg;
        const int lph = pp / PO, lpw = pp % PO;
        const int gpp = (hb * POR + lph) * PO + lpw;
        unsigned short* yr = yout + ((long)bimg * (PO * PO) + gpp) * (2 * CO);
        #pragma unroll
        for (int nt = 0; nt < NT; nt++) {
            const int co = co0 + (wn * NT + nt) * 16 + lm;
            const i32x4 aL = accL[mt][nt], aH = accH[mt][nt];
            int s0 = aH[0] * 256 + aL[0];
            int s1 = aH[1] * 256 + aL[1];
            int s2 = aH[2] * 256 + aL[2];
            int s3 = aH[3] * 256 + aL[3];
            int sm = s0 > s1 ? s0 : s1;
            int sn = s2 > s3 ? s2 : s3;
            sm = sm > sn ? sm : sn;
            float o = fmaxf(dq * (float)sm + bias[co], 0.f);
            tmax = fmaxf(tmax, o);
            unsigned short hi = f2bf(o);
            unsigned short lo = f2bf(o - bf2f(hi));
            yr[co] = hi;
            yr[CO + co] = lo;
        }
    }
    if (amax_out) {
        #pragma unroll
        for (int off = 32; off > 0; off >>= 1)
            tmax = fmaxf(tmax, __shfl_down(tmax, off, 64));
        if (lane == 0) redm[wid] = tmax;
        __syncthreads();
        if (tid == 0) {
            float m = fmaxf(fmaxf(redm[0], redm[1]), fmaxf(redm[2], redm[3]));
            atomicMax(amax_out, __float_as_int(m));
        }
    }
}

// ---------------------------------------------------------------------------
// fc1 MFMA (bf16, unchanged): K=8192 hi/lo slots, split-K, reg-pipelined.
// ---------------------------------------------------------------------------
template <int S>
__global__ __launch_bounds__(256) void fc1_mfma(
        const unsigned short* __restrict__ A,
        const unsigned short* __restrict__ Bw,
        float* __restrict__ parts) {
    constexpr int KCH = 8192 / S;
    constexpr int NSTEP = KCH / 32;
    const int m0 = blockIdx.x * 128;
    const int n0 = blockIdx.y * 128;
    const int s = blockIdx.z;
    const int tid = threadIdx.x;
    const int lane = tid & 63, wid = tid >> 6;
    const int wm = wid >> 1, wn = wid & 1;
    const int lm = lane & 15, kg = lane >> 4;

    const long k0 = (long)s * KCH + kg * 8;
    const unsigned short* ap[4];
    const unsigned short* bp[4];
    #pragma unroll
    for (int t = 0; t < 4; t++) {
        ap[t] = A + (long)(m0 + wm * 64 + t * 16 + lm) * 8192 + k0;
        bp[t] = Bw + (long)(n0 + wn * 64 + t * 16 + lm) * 8192 + k0;
    }

    f32x4 acc[4][4] = {};
    short8 Ab[2][4], Bb[2][4];
    #pragma unroll
    for (int t = 0; t < 4; t++) {
        Ab[0][t] = *(const short8*)(ap[t]);
        Bb[0][t] = *(const short8*)(bp[t]);
    }

    #pragma unroll 2
    for (int st = 0; st < NSTEP; ++st) {
        const int cur = st & 1, nxt = cur ^ 1;
        if (st + 1 < NSTEP) {
            const int off = (st + 1) * 32;
            #pragma unroll
            for (int t = 0; t < 4; t++) {
                Ab[nxt][t] = *(const short8*)(ap[t] + off);
                Bb[nxt][t] = *(const short8*)(bp[t] + off);
            }
        }
        #pragma unroll
        for (int mt = 0; mt < 4; mt++)
            #pragma unroll
            for (int nt = 0; nt < 4; nt++)
                acc[mt][nt] = __builtin_amdgcn_mfma_f32_16x16x32_bf16(
                    Ab[cur][mt], Bb[cur][nt], acc[mt][nt], 0, 0, 0);
    }

    #pragma unroll
    for (int mt = 0; mt < 4; mt++) {
        #pragma unroll
        for (int r = 0; r < 4; r++) {
            const int b = m0 + wm * 64 + mt * 16 + kg * 4 + r;
            #pragma unroll
            for (int nt = 0; nt < 4; nt++) {
                const int j = n0 + wn * 64 + nt * 16 + lm;
                parts[((long)s * 1024 + b) * 256 + j] = acc[mt][nt][r];
            }
        }
    }
}

template <int S>
__global__ void fc1_reduce(const float* __restrict__ parts,
                           const double* __restrict__ scr,
                           const float* __restrict__ bias,
                           float* __restrict__ f1) {
    const int idx = blockIdx.x * blockDim.x + threadIdx.x;  // < 262144
    const int j = idx & 255;
    float s = 0.f;
    #pragma unroll
    for (int p = 0; p < S; p++) s += parts[(long)p * 262144 + idx];
    const double c2 = scr[2];
    const float alpha = (float)(scr[1] / (c2 > 1.0 ? c2 : 1.0));
    f1[idx] = fmaxf(alpha * s + bias[j], 0.f);
}

__global__ void fc2_kernel(const float* __restrict__ a,
                           const float* __restrict__ wt,
                           const float* __restrict__ bias,
                           float* __restrict__ out, int B) {
    const int idx = blockIdx.x * blockDim.x + threadIdx.x;
    if (idx >= B * 10) return;
    const int k = idx % 10;
    const int b = idx / 10;
    const float* ar = a + (long)b * 256;
    const float* wr = wt + (long)k * 256;
    float acc = 0.f;
    #pragma unroll 4
    for (int i = 0; i < 256; i++) acc += ar[i] * wr[i];
    out[idx] = acc + bias[k];
}

extern "C" void kernel_launch(void* const* d_in, const int* in_sizes, int n_in,
                              void* d_out, int out_size, void* d_ws, size_t ws_size,
                              hipStream_t stream) {
    const float* x   = (const float*)d_in[0];
    const float* w1  = (const float*)d_in[1];
    const float* b1  = (const float*)d_in[2];
    const float* w2  = (const float*)d_in[3];
    const float* b2  = (const float*)d_in[4];
    const float* w3  = (const float*)d_in[5];
    const float* b3  = (const float*)d_in[6];
    const float* wf1 = (const float*)d_in[7];
    const float* bf1 = (const float*)d_in[8];
    const float* wf2 = (const float*)d_in[9];
    const float* bf2 = (const float*)d_in[10];
    float* out = (float*)d_out;
    float* ws = (float*)d_ws;

    const int B = 1024;

    float*          wt1   = ws + WS_WT1;
    signed char*    w2p8  = (signed char*)(ws + WS_W2P);
    signed char*    w3p8  = (signed char*)(ws + WS_W3P);
    unsigned short* wtf1b = (unsigned short*)(ws + WS_WTF1);
    float*          wtf2  = ws + WS_WTF2;
    unsigned short* a1p   = (unsigned short*)(ws + WS_A1);
    unsigned short* a2p   = (unsigned short*)(ws + WS_A2);
    unsigned short* a3p   = (unsigned short*)(ws + WS_A3);
    float*          f1    = ws + WS_F1;
    double*         scr   = (double*)(ws + WS_SCR);
    int*            amax1 = (int*)(scr + 20);
    int*            amax2 = amax1 + 1;
    float*          parts = ws + WS_A1;   // alias: a1 dead after conv2

    hipMemsetAsync(scr, 0, 22 * sizeof(double), stream);

    TernArgs ta;
    ta.w[0] = w1;  ta.n[0] = N_WT1;
    ta.w[1] = w2;  ta.n[1] = 128 * 64 * 9;
    ta.w[2] = w3;  ta.n[2] = 256 * 128 * 9;
    ta.w[3] = wf1; ta.n[3] = 256 * 4096;
    ta.w[4] = wf2; ta.n[4] = 10 * 256;

    hipLaunchKernelGGL(tern_stats1, dim3(128, 5), dim3(256), 0, stream, ta, scr);
    hipLaunchKernelGGL(tern_stats2, dim3(128, 5), dim3(256), 0, stream, ta, scr);
    hipLaunchKernelGGL(tern_write_all, dim3(128, 5), dim3(256), 0, stream,
                       ta, scr, wt1, w2p8, w3p8, wtf1b, wtf2);

    // conv1: fp32 direct -> a1 (bf16 hi/lo rows) + amax1
    hipLaunchKernelGGL(conv1_kernel, dim3(B, 8), dim3(256), 0, stream,
                       x, wt1, b1, a1p, amax1);

    // conv2: CI=64, HI=16, CO=128, HB=4 -> 4096 blocks, i8 MFMA
    hipLaunchKernelGGL((conv_i8<64, 16, 128, 4, 1>), dim3(B * 4, 1), dim3(256),
                       0, stream, a1p, w2p8, b2, scr + 4, amax1, amax2, a2p);

    // conv3: CI=128, HI=8, CO=256, HB=1, 2 co-halves -> 1024x2 blocks
    hipLaunchKernelGGL((conv_i8<128, 8, 256, 1, 2>), dim3(B, 2), dim3(256),
                       0, stream, a2p, w3p8, b3, scr + 8, amax2, (int*)nullptr,
                       a3p);

    // fc1: MFMA split-K + reduce(alpha+bias+relu)
    hipLaunchKernelGGL((fc1_mfma<FC1_S>), dim3(8, 2, FC1_S), dim3(256), 0, stream,
                       a3p, wtf1b, parts);
    hipLaunchKernelGGL((fc1_reduce<FC1_S>), dim3(1024), dim3(256), 0, stream,
                       parts, scr + 12, bf1, f1);

    // fc2
    hipLaunchKernelGGL(fc2_kernel, dim3((B * 10 + 255) / 256), dim3(256), 0,
                       stream, f1, wtf2, bf2, out, B);
}

// Round 8
// 386.076 us; speedup vs baseline: 1.0554x; 1.0554x over previous
//
#include <hip/hip_runtime.h>
#include <hip/hip_bf16.h>

// ---------------------------------------------------------------------------
// TernaryCIFAR10Net on MI355X — Round 8:
//   conv1 rewritten: block = (image, quadrant) covering all 64 co; input
//   patch + weights staged in LDS; thread = (pooled px, 16-co group);
//   fully-coalesced full-line fp32 writes (a1 is now fp32 rows).
//   conv2 (i8 MFMA) staging quantizes from fp32 a1 directly.
//   conv3 (i8 MFMA, bf16-pair input), fc1 (bf16 MFMA split-K), fc2,
//   ternarize unchanged from R7.
// ---------------------------------------------------------------------------

typedef __attribute__((ext_vector_type(8))) short short8;
typedef __attribute__((ext_vector_type(4))) float f32x4;
typedef __attribute__((ext_vector_type(4))) int i32x4;

__device__ __forceinline__ unsigned short f2bf(float x) {
    unsigned u = __float_as_uint(x);
    return (unsigned short)((u + 0x7fffu + ((u >> 16) & 1u)) >> 16);  // RNE
}
__device__ __forceinline__ float bf2f(unsigned short b) {
    return __uint_as_float(((unsigned)b) << 16);
}

// workspace layout (4-byte units)
#define WS_WT1   0
#define N_WT1    (64*3*3*3)
#define WS_W2P   (WS_WT1 + N_WT1)
#define N_W2P    (9*128*64)
#define WS_W3P   (WS_W2P + N_W2P)
#define N_W3P    (9*256*128)
#define WS_WTF1  (WS_W3P + N_W3P)
#define N_WTF1   (256*4096)            // ushort signs [256][8192]
#define WS_WTF2  (WS_WTF1 + N_WTF1)
#define N_WTF2   (10*256)
#define WS_A1    (WS_WTF2 + N_WTF2)
#define N_A1     (1024*256*64)         // a1: [B][256px][64 fp32]; parts alias
#define WS_A2    (WS_A1 + N_A1)
#define N_A2     (1024*64*128)         // a2: [B][64px][256 ushort] (hi/lo bf16)
#define WS_A3    (WS_A2 + N_A2)
#define N_A3     (1024*16*256)         // a3: [B][16px][512 ushort]
#define WS_F1    (WS_A3 + N_A3)
#define N_F1     (1024*256)
#define WS_SCR   (WS_F1 + N_F1)

#define FC1_S    16

struct TernArgs {
    const float* w[5];
    int n[5];
};

// ---------------------------------------------------------------------------
// Ternarize stats (fused over 5 weights): scr[wi] = {sum|w|, msum, count, pad}
// ---------------------------------------------------------------------------
__global__ void tern_stats1(TernArgs ta, double* __restrict__ scr) {
    const int wi = blockIdx.y;
    const float* __restrict__ w = ta.w[wi];
    const int n = ta.n[wi];
    double s = 0.0;
    for (int i = blockIdx.x * blockDim.x + threadIdx.x; i < n;
         i += gridDim.x * blockDim.x)
        s += (double)fabsf(w[i]);
    #pragma unroll
    for (int off = 32; off > 0; off >>= 1) s += __shfl_down(s, off, 64);
    __shared__ double red[4];
    const int lane = threadIdx.x & 63, wv = threadIdx.x >> 6;
    if (lane == 0) red[wv] = s;
    __syncthreads();
    if (threadIdx.x == 0)
        atomicAdd(scr + wi * 4, red[0] + red[1] + red[2] + red[3]);
}

__global__ void tern_stats2(TernArgs ta, double* __restrict__ scr) {
    const int wi = blockIdx.y;
    const float* __restrict__ w = ta.w[wi];
    const int n = ta.n[wi];
    const float delta = (float)(0.7 * scr[wi * 4] / (double)n);
    double ms = 0.0, cnt = 0.0;
    for (int i = blockIdx.x * blockDim.x + threadIdx.x; i < n;
         i += gridDim.x * blockDim.x) {
        float a = fabsf(w[i]);
        if (a > delta) { ms += (double)a; cnt += 1.0; }
    }
    #pragma unroll
    for (int off = 32; off > 0; off >>= 1) {
        ms += __shfl_down(ms, off, 64);
        cnt += __shfl_down(cnt, off, 64);
    }
    __shared__ double redm[4], redc[4];
    const int lane = threadIdx.x & 63, wv = threadIdx.x >> 6;
    if (lane == 0) { redm[wv] = ms; redc[wv] = cnt; }
    __syncthreads();
    if (threadIdx.x == 0) {
        atomicAdd(scr + wi * 4 + 1, redm[0] + redm[1] + redm[2] + redm[3]);
        atomicAdd(scr + wi * 4 + 2, redc[0] + redc[1] + redc[2] + redc[3]);
    }
}

// ---------------------------------------------------------------------------
// Fused writer (same as R7).
// ---------------------------------------------------------------------------
__global__ void tern_write_all(TernArgs ta, const double* __restrict__ scr,
                               float* __restrict__ wt1,
                               signed char* __restrict__ w2p8,
                               signed char* __restrict__ w3p8,
                               unsigned short* __restrict__ wtf1b,
                               float* __restrict__ wtf2) {
    const int wi = blockIdx.y;
    const float* __restrict__ w = ta.w[wi];
    const int n = ta.n[wi];
    const double* sc = scr + wi * 4;
    const float delta = (float)(0.7 * sc[0] / (double)n);
    const int i0 = blockIdx.x * blockDim.x + threadIdx.x;
    const int stride = gridDim.x * blockDim.x;

    if (wi == 0 || wi == 4) {
        const double c = sc[2];
        const float alpha = (float)(sc[1] / (c > 1.0 ? c : 1.0));
        float* dst = (wi == 0) ? wt1 : wtf2;
        for (int i = i0; i < n; i += stride) {
            float v = w[i];
            dst[i] = (fabsf(v) > delta) ? (v > 0.0f ? alpha : -alpha) : 0.0f;
        }
    } else if (wi == 1 || wi == 2) {
        const int CIc = (wi == 1) ? 64 : 128;
        const int COc = (wi == 1) ? 128 : 256;
        signed char* dst = (wi == 1) ? w2p8 : w3p8;
        for (int i = i0; i < n; i += stride) {
            const int co = i / (CIc * 9);
            const int r = i % (CIc * 9);
            const int ci = r / 9, tap = r % 9;
            float v = w[i];
            signed char s = (fabsf(v) > delta) ? (v > 0.0f ? 1 : -1) : 0;
            dst[(tap * COc + co) * CIc + ci] = s;
        }
    } else {  // wi == 3: fc1 signs, hi and lo slots
        for (int i = i0; i < n; i += stride) {
            const int j = i >> 12;
            const int k = i & 4095;
            const int c = k >> 4, px = k & 15;
            float v = w[i];
            unsigned short s = (fabsf(v) > delta) ? (v > 0.0f ? 0x3f80 : 0xbf80) : 0;
            unsigned short* row = wtf1b + ((long)j << 13) + px * 512 + c;
            row[0] = s;
            row[256] = s;
        }
    }
}

// ---------------------------------------------------------------------------
// conv1 (R8): block = (img, quadrant). Quadrant = 8x8 pooled px; all 64 co.
// Input patch 18x18x3 + all weights staged in LDS. Thread = (pooled px,
// 16-co group): 1728 FMA vs ~60 vector LDS reads -> VALU-bound.
// Output a1 fp32 rows [px][64]; 4 consecutive lanes write one full 256-B row.
// ---------------------------------------------------------------------------
__global__ __launch_bounds__(256) void conv1_q(
        const float* __restrict__ x, const float* __restrict__ wt,
        const float* __restrict__ bias, float* __restrict__ y,
        int* __restrict__ amax) {
    constexpr int HI = 32, CI = 3, CO = 64, PO = 16;
    constexpr int PP = 20;                       // patch pitch (floats)
    __shared__ float patch[CI * 18 * PP];        // 4.8 KB
    __shared__ float sw[CO * CI * 12];           // 9.2 KB
    __shared__ float redm[4];

    const int b = blockIdx.x >> 2;
    const int quad = blockIdx.x & 3;
    const int tid = threadIdx.x;

    // stage weights [co][ci][12]
    for (int i = tid; i < CO * CI * 9; i += 256) {
        const int co = i / 27;
        const int r = i % 27;
        const int ci = r / 9, k = r % 9;
        sw[(co * CI + ci) * 12 + k] = wt[i];
    }
    // stage input patch (halo zero-filled)
    const int qh = (quad >> 1) * 16, qw = (quad & 1) * 16;   // input-space origin
    for (int i = tid; i < CI * 18 * 18; i += 256) {
        const int ci = i / 324;
        const int r = (i % 324) / 18;
        const int c = i % 18;
        const int h = qh - 1 + r, w = qw - 1 + c;
        float v = 0.f;
        if ((unsigned)h < (unsigned)HI && (unsigned)w < (unsigned)HI)
            v = x[(((long)b * CI + ci) * HI + h) * HI + w];
        patch[(ci * 18 + r) * PP + c] = v;
    }
    __syncthreads();

    const int pxq = tid >> 2;                    // 0..63 quadrant-local pooled px
    const int cg = tid & 3;                      // co-group of 16
    const int lph = pxq >> 3, lpw = pxq & 7;

    float acc[16][4];
    #pragma unroll
    for (int c = 0; c < 16; c++)
        #pragma unroll
        for (int q = 0; q < 4; q++) acc[c][q] = 0.f;

    for (int ci = 0; ci < CI; ci++) {
        float p[4][4];
        #pragma unroll
        for (int r = 0; r < 4; r++)
            #pragma unroll
            for (int c = 0; c < 4; c++)
                p[r][c] = patch[(ci * 18 + 2 * lph + r) * PP + 2 * lpw + c];
        #pragma unroll
        for (int c = 0; c < 16; c++) {
            const int co = cg * 16 + c;
            const float4* w4 = (const float4*)(sw + (co * CI + ci) * 12);
            const float4 wa = w4[0], wb = w4[1], wc = w4[2];
            const float wk[9] = {wa.x, wa.y, wa.z, wa.w,
                                 wb.x, wb.y, wb.z, wb.w, wc.x};
            #pragma unroll
            for (int kh = 0; kh < 3; kh++)
                #pragma unroll
                for (int kw = 0; kw < 3; kw++) {
                    const float wvv = wk[kh * 3 + kw];
                    acc[c][0] += wvv * p[kh][kw];
                    acc[c][1] += wvv * p[kh][kw + 1];
                    acc[c][2] += wvv * p[kh + 1][kw];
                    acc[c][3] += wvv * p[kh + 1][kw + 1];
                }
        }
    }

    // epilogue: 16 consecutive fp32 per thread; 4 lanes = one full pixel row
    const int gpx = ((quad >> 1) * 8 + lph) * PO + (quad & 1) * 8 + lpw;
    float* yr = y + ((long)b * 256 + gpx) * CO + cg * 16;
    float tmax = 0.f;
    #pragma unroll
    for (int c = 0; c < 16; c++) {
        float m = fmaxf(fmaxf(acc[c][0], acc[c][1]), fmaxf(acc[c][2], acc[c][3]));
        float o = fmaxf(m + bias[cg * 16 + c], 0.f);
        tmax = fmaxf(tmax, o);
        yr[c] = o;
    }
    #pragma unroll
    for (int off = 32; off > 0; off >>= 1)
        tmax = fmaxf(tmax, __shfl_down(tmax, off, 64));
    const int lane = tid & 63, wv = tid >> 6;
    if (lane == 0) redm[wv] = tmax;
    __syncthreads();
    if (tid == 0) {
        float m = fmaxf(fmaxf(redm[0], redm[1]), fmaxf(redm[2], redm[3]));
        atomicMax(amax, __float_as_int(m));
    }
}

// ---------------------------------------------------------------------------
// int8 MFMA conv (R7 + fp32-input staging variant).
// INF32: input rows are [CI fp32]; else [hi CI][lo CI] bf16.
// Staging quantizes to 15-bit fixed point (S = 32512/amax_in), q = qh*256+ql,
// both i8, into two LDS plane groups. mfma_i32_16x16x64_i8, exact i32 math.
// ---------------------------------------------------------------------------
template <int CI, int HI, int CO, int HB, int NBY, bool INF32>
__global__ __launch_bounds__(256) void conv_i8(
        const void* __restrict__ xin,
        const signed char* __restrict__ wp,     // [9][CO][CI] int8 signs
        const float* __restrict__ bias,
        const double* __restrict__ scr,         // layer {_, msum, count}
        const int* __restrict__ amax_in,
        int* __restrict__ amax_out,             // nullptr if unused
        unsigned short* __restrict__ yout) {
    constexpr int CH8 = CI / 64;            // K=64 chunks per plane
    constexpr int NITER = 9 * CH8;
    constexpr int HR = HI / HB;
    constexpr int ROWS = HR + 2;
    constexpr int COLS = HI + 2;
    constexpr int NPIX = ROWS * COLS;
    constexpr int PSTR = NPIX * 64 + 32;    // bytes per g-plane
    constexpr int PO = HI / 2;
    constexpr int POR = HR / 2;
    constexpr int MT = 2, NT = 4;

    __shared__ __align__(16) char X[2 * CH8 * PSTR];
    __shared__ float redm[4];

    const int bimg = blockIdx.x / HB;
    const int hb = blockIdx.x % HB;
    const int co0 = (NBY > 1) ? blockIdx.y * 128 : 0;
    const int tid = threadIdx.x;

    const float S = 32512.0f / fmaxf(__int_as_float(*amax_in), 1e-30f);

    // halo zero (borders only; disjoint from interior staging)
    constexpr int HALO = 2 * COLS + 2 * (ROWS - 2);
    for (int i = tid; i < HALO * 2 * CH8 * 4; i += 256) {
        const int u = i & 3;
        const int t = i >> 2;
        const int g = t % (2 * CH8);
        const int hp = t / (2 * CH8);
        int p;
        if (hp < COLS) p = hp;
        else if (hp < 2 * COLS) p = (ROWS - 1) * COLS + (hp - COLS);
        else {
            const int e = hp - 2 * COLS;
            p = (1 + (e >> 1)) * COLS + ((e & 1) ? (COLS - 1) : 0);
        }
        *(int4*)&X[g * PSTR + p * 64 + u * 16] = make_int4(0, 0, 0, 0);
    }

    // interior staging -> (ql, qh) planes, slot-swizzled
    for (int i = tid; i < ROWS * HI * (CI / 8); i += 256) {
        const int q8 = i % (CI / 8);
        const int t = i / (CI / 8);
        const int c = t % HI;
        const int r = t / HI;
        const int h = hb * HR + r - 1;
        if ((unsigned)h < (unsigned)HI) {
            const int c8 = q8 * 8;
            float f[8];
            if (INF32) {
                const float* pxr = (const float*)xin +
                    ((long)(bimg * HI + h) * HI + c) * CI + c8;
                const float4 va = *(const float4*)(pxr);
                const float4 vb = *(const float4*)(pxr + 4);
                f[0] = va.x; f[1] = va.y; f[2] = va.z; f[3] = va.w;
                f[4] = vb.x; f[5] = vb.y; f[6] = vb.z; f[7] = vb.w;
            } else {
                const unsigned short* pxr = (const unsigned short*)xin +
                    ((long)(bimg * HI + h) * HI + c) * (2 * CI);
                const uint4 vh = *(const uint4*)(pxr + c8);
                const uint4 vl = *(const uint4*)(pxr + CI + c8);
                const unsigned* hw = (const unsigned*)&vh;
                const unsigned* lw = (const unsigned*)&vl;
                #pragma unroll
                for (int j = 0; j < 8; j++) {
                    const unsigned hu = (j & 1) ? (hw[j >> 1] >> 16)
                                                : (hw[j >> 1] & 0xffffu);
                    const unsigned lu = (j & 1) ? (lw[j >> 1] >> 16)
                                                : (lw[j >> 1] & 0xffffu);
                    f[j] = __uint_as_float(hu << 16) + __uint_as_float(lu << 16);
                }
            }
            unsigned pl0 = 0, pl1 = 0, ph0 = 0, ph1 = 0;
            #pragma unroll
            for (int j = 0; j < 8; j++) {
                const int qi = (int)(f[j] * S + 0.5f);
                const int ql = (qi << 24) >> 24;       // sign-extended low byte
                const int qh = (qi - ql) >> 8;         // in [0,127]
                const int sh = (j & 3) * 8;
                if (j < 4) {
                    pl0 |= (unsigned)(ql & 255) << sh;
                    ph0 |= (unsigned)(qh & 255) << sh;
                } else {
                    pl1 |= (unsigned)(ql & 255) << sh;
                    ph1 |= (unsigned)(qh & 255) << sh;
                }
            }
            const int p = r * COLS + c + 1;
            const int ch = c8 >> 6;
            const int cc = c8 & 63;
            const int slot = ((cc >> 4) + (p >> 1)) & 3;
            const int base = p * 64 + slot * 16 + (cc & 15);
            *(uint2*)&X[ch * PSTR + base] = make_uint2(pl0, pl1);
            *(uint2*)&X[(CH8 + ch) * PSTR + base] = make_uint2(ph0, ph1);
        }
    }
    __syncthreads();

    const int lane = tid & 63;
    const int wid = tid >> 6;
    const int wm = wid >> 1;
    const int wn = wid & 1;
    const int lm = lane & 15;
    const int kg = lane >> 4;

    int pb[MT];
    #pragma unroll
    for (int mt = 0; mt < MT; mt++) {
        const int m = (wm * MT + mt) * 16 + lm;
        const int pp = m >> 2, sub = m & 3;
        const int lph = pp / PO, lpw = pp % PO;
        const int h = 2 * lph + (sub >> 1);
        const int w = 2 * lpw + (sub & 1);
        pb[mt] = h * COLS + w;
    }
    const signed char* bp[NT];
    #pragma unroll
    for (int nt = 0; nt < NT; nt++) {
        const int co = co0 + (wn * NT + nt) * 16 + lm;
        bp[nt] = wp + (long)co * CI + kg * 16;
    }

    i32x4 accL[MT][NT], accH[MT][NT];
    #pragma unroll
    for (int mt = 0; mt < MT; mt++)
        #pragma unroll
        for (int nt = 0; nt < NT; nt++) { accL[mt][nt] = 0; accH[mt][nt] = 0; }

    i32x4 Ab[2][MT][2], Bb[2][NT];
    #pragma unroll
    for (int nt = 0; nt < NT; nt++) Bb[0][nt] = *(const i32x4*)(bp[nt]);
    #pragma unroll
    for (int mt = 0; mt < MT; mt++) {
        const int p = pb[mt];
        const int ao = p * 64 + (((kg + (p >> 1)) & 3) << 4);
        Ab[0][mt][0] = *(const i32x4*)&X[ao];
        Ab[0][mt][1] = *(const i32x4*)&X[CH8 * PSTR + ao];
    }

    #pragma unroll 2
    for (int it = 0; it < NITER; ++it) {
        const int cur = it & 1, nxt = cur ^ 1;
        if (it + 1 < NITER) {
            const int it1 = it + 1;
            const int tap = it1 / CH8, ch = it1 % CH8;
            const int dtap = (tap / 3) * COLS + (tap % 3);
            const int woff = tap * CO * CI + ch * 64;
            #pragma unroll
            for (int nt = 0; nt < NT; nt++)
                Bb[nxt][nt] = *(const i32x4*)(bp[nt] + woff);
            #pragma unroll
            for (int mt = 0; mt < MT; mt++) {
                const int p = pb[mt] + dtap;
                const int ao = p * 64 + (((kg + (p >> 1)) & 3) << 4);
                Ab[nxt][mt][0] = *(const i32x4*)&X[ch * PSTR + ao];
                Ab[nxt][mt][1] = *(const i32x4*)&X[(CH8 + ch) * PSTR + ao];
            }
        }
        #pragma unroll
        for (int mt = 0; mt < MT; mt++)
            #pragma unroll
            for (int nt = 0; nt < NT; nt++) {
                accL[mt][nt] = __builtin_amdgcn_mfma_i32_16x16x64_i8(
                    Ab[cur][mt][0], Bb[cur][nt], accL[mt][nt], 0, 0, 0);
                accH[mt][nt] = __builtin_amdgcn_mfma_i32_16x16x64_i8(
                    Ab[cur][mt][1], Bb[cur][nt], accH[mt][nt], 0, 0, 0);
            }
    }

    // epilogue: sum = 256*accH + accL (exact i32); pool in int; dq + bias + relu
    const double c2 = scr[2];
    const float alpha = (float)(scr[1] / (c2 > 1.0 ? c2 : 1.0));
    const float dq = alpha / S;
    float tmax = 0.f;
    #pragma unroll
    for (int mt = 0; mt < MT; mt++) {
        const int pp = (wm * MT + mt) * 4 + kg;
        const int lph = pp / PO, lpw = pp % PO;
        const int gpp = (hb * POR + lph) * PO + lpw;
        unsigned short* yr = yout + ((long)bimg * (PO * PO) + gpp) * (2 * CO);
        #pragma unroll
        for (int nt = 0; nt < NT; nt++) {
            const int co = co0 + (wn * NT + nt) * 16 + lm;
            const i32x4 aL = accL[mt][nt], aH = accH[mt][nt];
            int s0 = aH[0] * 256 + aL[0];
            int s1 = aH[1] * 256 + aL[1];
            int s2 = aH[2] * 256 + aL[2];
            int s3 = aH[3] * 256 + aL[3];
            int sm = s0 > s1 ? s0 : s1;
            int sn = s2 > s3 ? s2 : s3;
            sm = sm > sn ? sm : sn;
            float o = fmaxf(dq * (float)sm + bias[co], 0.f);
            tmax = fmaxf(tmax, o);
            unsigned short hi = f2bf(o);
            unsigned short lo = f2bf(o - bf2f(hi));
            yr[co] = hi;
            yr[CO + co] = lo;
        }
    }
    if (amax_out) {
        #pragma unroll
        for (int off = 32; off > 0; off >>= 1)
            tmax = fmaxf(tmax, __shfl_down(tmax, off, 64));
        if (lane == 0) redm[wid] = tmax;
        __syncthreads();
        if (tid == 0) {
            float m = fmaxf(fmaxf(redm[0], redm[1]), fmaxf(redm[2], redm[3]));
            atomicMax(amax_out, __float_as_int(m));
        }
    }
}

// ---------------------------------------------------------------------------
// fc1 MFMA (bf16, unchanged): K=8192 hi/lo slots, split-K, reg-pipelined.
// ---------------------------------------------------------------------------
template <int S>
__global__ __launch_bounds__(256) void fc1_mfma(
        const unsigned short* __restrict__ A,
        const unsigned short* __restrict__ Bw,
        float* __restrict__ parts) {
    constexpr int KCH = 8192 / S;
    constexpr int NSTEP = KCH / 32;
    const int m0 = blockIdx.x * 128;
    const int n0 = blockIdx.y * 128;
    const int s = blockIdx.z;
    const int tid = threadIdx.x;
    const int lane = tid & 63, wid = tid >> 6;
    const int wm = wid >> 1, wn = wid & 1;
    const int lm = lane & 15, kg = lane >> 4;

    const long k0 = (long)s * KCH + kg * 8;
    const unsigned short* ap[4];
    const unsigned short* bp[4];
    #pragma unroll
    for (int t = 0; t < 4; t++) {
        ap[t] = A + (long)(m0 + wm * 64 + t * 16 + lm) * 8192 + k0;
        bp[t] = Bw + (long)(n0 + wn * 64 + t * 16 + lm) * 8192 + k0;
    }

    f32x4 acc[4][4] = {};
    short8 Ab[2][4], Bb[2][4];
    #pragma unroll
    for (int t = 0; t < 4; t++) {
        Ab[0][t] = *(const short8*)(ap[t]);
        Bb[0][t] = *(const short8*)(bp[t]);
    }

    #pragma unroll 2
    for (int st = 0; st < NSTEP; ++st) {
        const int cur = st & 1, nxt = cur ^ 1;
        if (st + 1 < NSTEP) {
            const int off = (st + 1) * 32;
            #pragma unroll
            for (int t = 0; t < 4; t++) {
                Ab[nxt][t] = *(const short8*)(ap[t] + off);
                Bb[nxt][t] = *(const short8*)(bp[t] + off);
            }
        }
        #pragma unroll
        for (int mt = 0; mt < 4; mt++)
            #pragma unroll
            for (int nt = 0; nt < 4; nt++)
                acc[mt][nt] = __builtin_amdgcn_mfma_f32_16x16x32_bf16(
                    Ab[cur][mt], Bb[cur][nt], acc[mt][nt], 0, 0, 0);
    }

    #pragma unroll
    for (int mt = 0; mt < 4; mt++) {
        #pragma unroll
        for (int r = 0; r < 4; r++) {
            const int b = m0 + wm * 64 + mt * 16 + kg * 4 + r;
            #pragma unroll
            for (int nt = 0; nt < 4; nt++) {
                const int j = n0 + wn * 64 + nt * 16 + lm;
                parts[((long)s * 1024 + b) * 256 + j] = acc[mt][nt][r];
            }
        }
    }
}

template <int S>
__global__ void fc1_reduce(const float* __restrict__ parts,
                           const double* __restrict__ scr,
                           const float* __restrict__ bias,
                           float* __restrict__ f1) {
    const int idx = blockIdx.x * blockDim.x + threadIdx.x;  // < 262144
    const int j = idx & 255;
    float s = 0.f;
    #pragma unroll
    for (int p = 0; p < S; p++) s += parts[(long)p * 262144 + idx];
    const double c2 = scr[2];
    const float alpha = (float)(scr[1] / (c2 > 1.0 ? c2 : 1.0));
    f1[idx] = fmaxf(alpha * s + bias[j], 0.f);
}

__global__ void fc2_kernel(const float* __restrict__ a,
                           const float* __restrict__ wt,
                           const float* __restrict__ bias,
                           float* __restrict__ out, int B) {
    const int idx = blockIdx.x * blockDim.x + threadIdx.x;
    if (idx >= B * 10) return;
    const int k = idx % 10;
    const int b = idx / 10;
    const float* ar = a + (long)b * 256;
    const float* wr = wt + (long)k * 256;
    float acc = 0.f;
    #pragma unroll 4
    for (int i = 0; i < 256; i++) acc += ar[i] * wr[i];
    out[idx] = acc + bias[k];
}

extern "C" void kernel_launch(void* const* d_in, const int* in_sizes, int n_in,
                              void* d_out, int out_size, void* d_ws, size_t ws_size,
                              hipStream_t stream) {
    const float* x   = (const float*)d_in[0];
    const float* w1  = (const float*)d_in[1];
    const float* b1  = (const float*)d_in[2];
    const float* w2  = (const float*)d_in[3];
    const float* b2  = (const float*)d_in[4];
    const float* w3  = (const float*)d_in[5];
    const float* b3  = (const float*)d_in[6];
    const float* wf1 = (const float*)d_in[7];
    const float* bf1 = (const float*)d_in[8];
    const float* wf2 = (const float*)d_in[9];
    const float* bf2 = (const float*)d_in[10];
    float* out = (float*)d_out;
    float* ws = (float*)d_ws;

    const int B = 1024;

    float*          wt1   = ws + WS_WT1;
    signed char*    w2p8  = (signed char*)(ws + WS_W2P);
    signed char*    w3p8  = (signed char*)(ws + WS_W3P);
    unsigned short* wtf1b = (unsigned short*)(ws + WS_WTF1);
    float*          wtf2  = ws + WS_WTF2;
    float*          a1f   = ws + WS_A1;
    unsigned short* a2p   = (unsigned short*)(ws + WS_A2);
    unsigned short* a3p   = (unsigned short*)(ws + WS_A3);
    float*          f1    = ws + WS_F1;
    double*         scr   = (double*)(ws + WS_SCR);
    int*            amax1 = (int*)(scr + 20);
    int*            amax2 = amax1 + 1;
    float*          parts = ws + WS_A1;   // alias: a1 dead after conv2

    hipMemsetAsync(scr, 0, 22 * sizeof(double), stream);

    TernArgs ta;
    ta.w[0] = w1;  ta.n[0] = N_WT1;
    ta.w[1] = w2;  ta.n[1] = 128 * 64 * 9;
    ta.w[2] = w3;  ta.n[2] = 256 * 128 * 9;
    ta.w[3] = wf1; ta.n[3] = 256 * 4096;
    ta.w[4] = wf2; ta.n[4] = 10 * 256;

    hipLaunchKernelGGL(tern_stats1, dim3(128, 5), dim3(256), 0, stream, ta, scr);
    hipLaunchKernelGGL(tern_stats2, dim3(128, 5), dim3(256), 0, stream, ta, scr);
    hipLaunchKernelGGL(tern_write_all, dim3(128, 5), dim3(256), 0, stream,
                       ta, scr, wt1, w2p8, w3p8, wtf1b, wtf2);

    // conv1: quadrant-tiled fp32 direct -> a1 fp32 rows + amax1
    hipLaunchKernelGGL(conv1_q, dim3(B * 4), dim3(256), 0, stream,
                       x, wt1, b1, a1f, amax1);

    // conv2: CI=64, HI=16, CO=128, HB=4, fp32 input -> 4096 blocks, i8 MFMA
    hipLaunchKernelGGL((conv_i8<64, 16, 128, 4, 1, true>), dim3(B * 4, 1),
                       dim3(256), 0, stream, a1f, w2p8, b2, scr + 4, amax1,
                       amax2, a2p);

    // conv3: CI=128, HI=8, CO=256, HB=1, 2 co-halves, bf16-pair input
    hipLaunchKernelGGL((conv_i8<128, 8, 256, 1, 2, false>), dim3(B, 2),
                       dim3(256), 0, stream, a2p, w3p8, b3, scr + 8, amax2,
                       (int*)nullptr, a3p);

    // fc1: MFMA split-K + reduce(alpha+bias+relu)
    hipLaunchKernelGGL((fc1_mfma<FC1_S>), dim3(8, 2, FC1_S), dim3(256), 0, stream,
                       a3p, wtf1b, parts);
    hipLaunchKernelGGL((fc1_reduce<FC1_S>), dim3(1024), dim3(256), 0, stream,
                       parts, scr + 12, bf1, f1);

    // fc2
    hipLaunchKernelGGL(fc2_kernel, dim3((B * 10 + 255) / 256), dim3(256), 0,
                       stream, f1, wtf2, bf2, out, B);
}

// Round 9
// 370.067 us; speedup vs baseline: 1.1011x; 1.0433x over previous
//
#include <hip/hip_runtime.h>
#include <hip/hip_bf16.h>

// ---------------------------------------------------------------------------
// TernaryCIFAR10Net on MI355X — Round 9:
//   conv1: weight LDS layout transposed to [ci][tap][co] (co-minor) so the
//   per-instruction weight reads of the 4 cg-groups land on disjoint bank
//   quads (2-way max, free) — was 4-way on EVERY weight b128 (24M conflict
//   cycles ≈ 40% of conv1). Loop restructured tap-major.
//   Everything else unchanged from R8 (conv2/conv3 i8 MFMA, fc1 bf16 MFMA
//   split-K, fused ternarize).
// ---------------------------------------------------------------------------

typedef __attribute__((ext_vector_type(8))) short short8;
typedef __attribute__((ext_vector_type(4))) float f32x4;
typedef __attribute__((ext_vector_type(4))) int i32x4;

__device__ __forceinline__ unsigned short f2bf(float x) {
    unsigned u = __float_as_uint(x);
    return (unsigned short)((u + 0x7fffu + ((u >> 16) & 1u)) >> 16);  // RNE
}
__device__ __forceinline__ float bf2f(unsigned short b) {
    return __uint_as_float(((unsigned)b) << 16);
}

// workspace layout (4-byte units)
#define WS_WT1   0
#define N_WT1    (64*3*3*3)
#define WS_W2P   (WS_WT1 + N_WT1)
#define N_W2P    (9*128*64)
#define WS_W3P   (WS_W2P + N_W2P)
#define N_W3P    (9*256*128)
#define WS_WTF1  (WS_W3P + N_W3P)
#define N_WTF1   (256*4096)            // ushort signs [256][8192]
#define WS_WTF2  (WS_WTF1 + N_WTF1)
#define N_WTF2   (10*256)
#define WS_A1    (WS_WTF2 + N_WTF2)
#define N_A1     (1024*256*64)         // a1: [B][256px][64 fp32]; parts alias
#define WS_A2    (WS_A1 + N_A1)
#define N_A2     (1024*64*128)         // a2: [B][64px][256 ushort] (hi/lo bf16)
#define WS_A3    (WS_A2 + N_A2)
#define N_A3     (1024*16*256)         // a3: [B][16px][512 ushort]
#define WS_F1    (WS_A3 + N_A3)
#define N_F1     (1024*256)
#define WS_SCR   (WS_F1 + N_F1)

#define FC1_S    16

struct TernArgs {
    const float* w[5];
    int n[5];
};

// ---------------------------------------------------------------------------
// Ternarize stats (fused over 5 weights): scr[wi] = {sum|w|, msum, count, pad}
// ---------------------------------------------------------------------------
__global__ void tern_stats1(TernArgs ta, double* __restrict__ scr) {
    const int wi = blockIdx.y;
    const float* __restrict__ w = ta.w[wi];
    const int n = ta.n[wi];
    double s = 0.0;
    for (int i = blockIdx.x * blockDim.x + threadIdx.x; i < n;
         i += gridDim.x * blockDim.x)
        s += (double)fabsf(w[i]);
    #pragma unroll
    for (int off = 32; off > 0; off >>= 1) s += __shfl_down(s, off, 64);
    __shared__ double red[4];
    const int lane = threadIdx.x & 63, wv = threadIdx.x >> 6;
    if (lane == 0) red[wv] = s;
    __syncthreads();
    if (threadIdx.x == 0)
        atomicAdd(scr + wi * 4, red[0] + red[1] + red[2] + red[3]);
}

__global__ void tern_stats2(TernArgs ta, double* __restrict__ scr) {
    const int wi = blockIdx.y;
    const float* __restrict__ w = ta.w[wi];
    const int n = ta.n[wi];
    const float delta = (float)(0.7 * scr[wi * 4] / (double)n);
    double ms = 0.0, cnt = 0.0;
    for (int i = blockIdx.x * blockDim.x + threadIdx.x; i < n;
         i += gridDim.x * blockDim.x) {
        float a = fabsf(w[i]);
        if (a > delta) { ms += (double)a; cnt += 1.0; }
    }
    #pragma unroll
    for (int off = 32; off > 0; off >>= 1) {
        ms += __shfl_down(ms, off, 64);
        cnt += __shfl_down(cnt, off, 64);
    }
    __shared__ double redm[4], redc[4];
    const int lane = threadIdx.x & 63, wv = threadIdx.x >> 6;
    if (lane == 0) { redm[wv] = ms; redc[wv] = cnt; }
    __syncthreads();
    if (threadIdx.x == 0) {
        atomicAdd(scr + wi * 4 + 1, redm[0] + redm[1] + redm[2] + redm[3]);
        atomicAdd(scr + wi * 4 + 2, redc[0] + redc[1] + redc[2] + redc[3]);
    }
}

// ---------------------------------------------------------------------------
// Fused writer (same as R8).
// ---------------------------------------------------------------------------
__global__ void tern_write_all(TernArgs ta, const double* __restrict__ scr,
                               float* __restrict__ wt1,
                               signed char* __restrict__ w2p8,
                               signed char* __restrict__ w3p8,
                               unsigned short* __restrict__ wtf1b,
                               float* __restrict__ wtf2) {
    const int wi = blockIdx.y;
    const float* __restrict__ w = ta.w[wi];
    const int n = ta.n[wi];
    const double* sc = scr + wi * 4;
    const float delta = (float)(0.7 * sc[0] / (double)n);
    const int i0 = blockIdx.x * blockDim.x + threadIdx.x;
    const int stride = gridDim.x * blockDim.x;

    if (wi == 0 || wi == 4) {
        const double c = sc[2];
        const float alpha = (float)(sc[1] / (c > 1.0 ? c : 1.0));
        float* dst = (wi == 0) ? wt1 : wtf2;
        for (int i = i0; i < n; i += stride) {
            float v = w[i];
            dst[i] = (fabsf(v) > delta) ? (v > 0.0f ? alpha : -alpha) : 0.0f;
        }
    } else if (wi == 1 || wi == 2) {
        const int CIc = (wi == 1) ? 64 : 128;
        const int COc = (wi == 1) ? 128 : 256;
        signed char* dst = (wi == 1) ? w2p8 : w3p8;
        for (int i = i0; i < n; i += stride) {
            const int co = i / (CIc * 9);
            const int r = i % (CIc * 9);
            const int ci = r / 9, tap = r % 9;
            float v = w[i];
            signed char s = (fabsf(v) > delta) ? (v > 0.0f ? 1 : -1) : 0;
            dst[(tap * COc + co) * CIc + ci] = s;
        }
    } else {  // wi == 3: fc1 signs, hi and lo slots
        for (int i = i0; i < n; i += stride) {
            const int j = i >> 12;
            const int k = i & 4095;
            const int c = k >> 4, px = k & 15;
            float v = w[i];
            unsigned short s = (fabsf(v) > delta) ? (v > 0.0f ? 0x3f80 : 0xbf80) : 0;
            unsigned short* row = wtf1b + ((long)j << 13) + px * 512 + c;
            row[0] = s;
            row[256] = s;
        }
    }
}

// ---------------------------------------------------------------------------
// conv1 (R9): block = (img, quadrant); 8x8 pooled px x all 64 co.
// Weights in LDS as [ci][tap][co] (co-minor): per-instruction reads of the 4
// cg groups hit disjoint bank quads (2-way max). Patch reads <=2-way.
// Output a1 fp32 rows [px][64]; 4 lanes = one full 256-B pixel row.
// ---------------------------------------------------------------------------
__global__ __launch_bounds__(256) void conv1_q(
        const float* __restrict__ x, const float* __restrict__ wt,
        const float* __restrict__ bias, float* __restrict__ y,
        int* __restrict__ amax) {
    constexpr int HI = 32, CI = 3, CO = 64, PO = 16;
    constexpr int PP = 20;                       // patch pitch (floats)
    __shared__ float patch[CI * 18 * PP];        // 4.8 KB
    __shared__ float sw[CI * 9 * CO];            // 6.9 KB, [ci*9+tap][co]
    __shared__ float redm[4];

    const int b = blockIdx.x >> 2;
    const int quad = blockIdx.x & 3;
    const int tid = threadIdx.x;

    // stage weights transposed: wt[co*27 + r] -> sw[r*64 + co]  (r = ci*9+tap)
    for (int i = tid; i < CO * CI * 9; i += 256) {
        const int co = i / 27;
        const int r = i % 27;
        sw[r * CO + co] = wt[i];
    }
    // stage input patch (halo zero-filled)
    const int qh = (quad >> 1) * 16, qw = (quad & 1) * 16;   // input-space origin
    for (int i = tid; i < CI * 18 * 18; i += 256) {
        const int ci = i / 324;
        const int r = (i % 324) / 18;
        const int c = i % 18;
        const int h = qh - 1 + r, w = qw - 1 + c;
        float v = 0.f;
        if ((unsigned)h < (unsigned)HI && (unsigned)w < (unsigned)HI)
            v = x[(((long)b * CI + ci) * HI + h) * HI + w];
        patch[(ci * 18 + r) * PP + c] = v;
    }
    __syncthreads();

    const int pxq = tid >> 2;                    // 0..63 quadrant-local pooled px
    const int cg = tid & 3;                      // co-group of 16
    const int lph = pxq >> 3, lpw = pxq & 7;

    float acc[16][4];
    #pragma unroll
    for (int c = 0; c < 16; c++)
        #pragma unroll
        for (int q = 0; q < 4; q++) acc[c][q] = 0.f;

    for (int ci = 0; ci < CI; ci++) {
        float p[4][4];
        #pragma unroll
        for (int r = 0; r < 4; r++)
            #pragma unroll
            for (int c = 0; c < 4; c++)
                p[r][c] = patch[(ci * 18 + 2 * lph + r) * PP + 2 * lpw + c];
        #pragma unroll
        for (int kh = 0; kh < 3; kh++)
            #pragma unroll
            for (int kw = 0; kw < 3; kw++) {
                const float4* wv = (const float4*)
                    &sw[((ci * 3 + kh) * 3 + kw) * CO + cg * 16];
                const float4 w0 = wv[0], w1 = wv[1], w2 = wv[2], w3 = wv[3];
                const float w16[16] = {w0.x, w0.y, w0.z, w0.w,
                                       w1.x, w1.y, w1.z, w1.w,
                                       w2.x, w2.y, w2.z, w2.w,
                                       w3.x, w3.y, w3.z, w3.w};
                const float p00 = p[kh][kw], p01 = p[kh][kw + 1];
                const float p10 = p[kh + 1][kw], p11 = p[kh + 1][kw + 1];
                #pragma unroll
                for (int c = 0; c < 16; c++) {
                    const float wvv = w16[c];
                    acc[c][0] += wvv * p00;
                    acc[c][1] += wvv * p01;
                    acc[c][2] += wvv * p10;
                    acc[c][3] += wvv * p11;
                }
            }
    }

    // epilogue: 16 consecutive fp32 per thread; 4 lanes = one full pixel row
    const int gpx = ((quad >> 1) * 8 + lph) * PO + (quad & 1) * 8 + lpw;
    float* yr = y + ((long)b * 256 + gpx) * CO + cg * 16;
    float tmax = 0.f;
    #pragma unroll
    for (int c = 0; c < 16; c++) {
        float m = fmaxf(fmaxf(acc[c][0], acc[c][1]), fmaxf(acc[c][2], acc[c][3]));
        float o = fmaxf(m + bias[cg * 16 + c], 0.f);
        tmax = fmaxf(tmax, o);
        yr[c] = o;
    }
    #pragma unroll
    for (int off = 32; off > 0; off >>= 1)
        tmax = fmaxf(tmax, __shfl_down(tmax, off, 64));
    const int lane = tid & 63, wv2 = tid >> 6;
    if (lane == 0) redm[wv2] = tmax;
    __syncthreads();
    if (tid == 0) {
        float m = fmaxf(fmaxf(redm[0], redm[1]), fmaxf(redm[2], redm[3]));
        atomicMax(amax, __float_as_int(m));
    }
}

// ---------------------------------------------------------------------------
// int8 MFMA conv (unchanged from R8).
// INF32: input rows are [CI fp32]; else [hi CI][lo CI] bf16.
// ---------------------------------------------------------------------------
template <int CI, int HI, int CO, int HB, int NBY, bool INF32>
__global__ __launch_bounds__(256) void conv_i8(
        const void* __restrict__ xin,
        const signed char* __restrict__ wp,     // [9][CO][CI] int8 signs
        const float* __restrict__ bias,
        const double* __restrict__ scr,         // layer {_, msum, count}
        const int* __restrict__ amax_in,
        int* __restrict__ amax_out,             // nullptr if unused
        unsigned short* __restrict__ yout) {
    constexpr int CH8 = CI / 64;            // K=64 chunks per plane
    constexpr int NITER = 9 * CH8;
    constexpr int HR = HI / HB;
    constexpr int ROWS = HR + 2;
    constexpr int COLS = HI + 2;
    constexpr int NPIX = ROWS * COLS;
    constexpr int PSTR = NPIX * 64 + 32;    // bytes per g-plane
    constexpr int PO = HI / 2;
    constexpr int POR = HR / 2;
    constexpr int MT = 2, NT = 4;

    __shared__ __align__(16) char X[2 * CH8 * PSTR];
    __shared__ float redm[4];

    const int bimg = blockIdx.x / HB;
    const int hb = blockIdx.x % HB;
    const int co0 = (NBY > 1) ? blockIdx.y * 128 : 0;
    const int tid = threadIdx.x;

    const float S = 32512.0f / fmaxf(__int_as_float(*amax_in), 1e-30f);

    // halo zero (borders only; disjoint from interior staging)
    constexpr int HALO = 2 * COLS + 2 * (ROWS - 2);
    for (int i = tid; i < HALO * 2 * CH8 * 4; i += 256) {
        const int u = i & 3;
        const int t = i >> 2;
        const int g = t % (2 * CH8);
        const int hp = t / (2 * CH8);
        int p;
        if (hp < COLS) p = hp;
        else if (hp < 2 * COLS) p = (ROWS - 1) * COLS + (hp - COLS);
        else {
            const int e = hp - 2 * COLS;
            p = (1 + (e >> 1)) * COLS + ((e & 1) ? (COLS - 1) : 0);
        }
        *(int4*)&X[g * PSTR + p * 64 + u * 16] = make_int4(0, 0, 0, 0);
    }

    // interior staging -> (ql, qh) planes, slot-swizzled
    for (int i = tid; i < ROWS * HI * (CI / 8); i += 256) {
        const int q8 = i % (CI / 8);
        const int t = i / (CI / 8);
        const int c = t % HI;
        const int r = t / HI;
        const int h = hb * HR + r - 1;
        if ((unsigned)h < (unsigned)HI) {
            const int c8 = q8 * 8;
            float f[8];
            if (INF32) {
                const float* pxr = (const float*)xin +
                    ((long)(bimg * HI + h) * HI + c) * CI + c8;
                const float4 va = *(const float4*)(pxr);
                const float4 vb = *(const float4*)(pxr + 4);
                f[0] = va.x; f[1] = va.y; f[2] = va.z; f[3] = va.w;
                f[4] = vb.x; f[5] = vb.y; f[6] = vb.z; f[7] = vb.w;
            } else {
                const unsigned short* pxr = (const unsigned short*)xin +
                    ((long)(bimg * HI + h) * HI + c) * (2 * CI);
                const uint4 vh = *(const uint4*)(pxr + c8);
                const uint4 vl = *(const uint4*)(pxr + CI + c8);
                const unsigned* hw = (const unsigned*)&vh;
                const unsigned* lw = (const unsigned*)&vl;
                #pragma unroll
                for (int j = 0; j < 8; j++) {
                    const unsigned hu = (j & 1) ? (hw[j >> 1] >> 16)
                                                : (hw[j >> 1] & 0xffffu);
                    const unsigned lu = (j & 1) ? (lw[j >> 1] >> 16)
                                                : (lw[j >> 1] & 0xffffu);
                    f[j] = __uint_as_float(hu << 16) + __uint_as_float(lu << 16);
                }
            }
            unsigned pl0 = 0, pl1 = 0, ph0 = 0, ph1 = 0;
            #pragma unroll
            for (int j = 0; j < 8; j++) {
                const int qi = (int)(f[j] * S + 0.5f);
                const int ql = (qi << 24) >> 24;       // sign-extended low byte
                const int qh = (qi - ql) >> 8;         // in [0,127]
                const int sh = (j & 3) * 8;
                if (j < 4) {
                    pl0 |= (unsigned)(ql & 255) << sh;
                    ph0 |= (unsigned)(qh & 255) << sh;
                } else {
                    pl1 |= (unsigned)(ql & 255) << sh;
                    ph1 |= (unsigned)(qh & 255) << sh;
                }
            }
            const int p = r * COLS + c + 1;
            const int ch = c8 >> 6;
            const int cc = c8 & 63;
            const int slot = ((cc >> 4) + (p >> 1)) & 3;
            const int base = p * 64 + slot * 16 + (cc & 15);
            *(uint2*)&X[ch * PSTR + base] = make_uint2(pl0, pl1);
            *(uint2*)&X[(CH8 + ch) * PSTR + base] = make_uint2(ph0, ph1);
        }
    }
    __syncthreads();

    const int lane = tid & 63;
    const int wid = tid >> 6;
    const int wm = wid >> 1;
    const int wn = wid & 1;
    const int lm = lane & 15;
    const int kg = lane >> 4;

    int pb[MT];
    #pragma unroll
    for (int mt = 0; mt < MT; mt++) {
        const int m = (wm * MT + mt) * 16 + lm;
        const int pp = m >> 2, sub = m & 3;
        const int lph = pp / PO, lpw = pp % PO;
        const int h = 2 * lph + (sub >> 1);
        const int w = 2 * lpw + (sub & 1);
        pb[mt] = h * COLS + w;
    }
    const signed char* bp[NT];
    #pragma unroll
    for (int nt = 0; nt < NT; nt++) {
        const int co = co0 + (wn * NT + nt) * 16 + lm;
        bp[nt] = wp + (long)co * CI + kg * 16;
    }

    i32x4 accL[MT][NT], accH[MT][NT];
    #pragma unroll
    for (int mt = 0; mt < MT; mt++)
        #pragma unroll
        for (int nt = 0; nt < NT; nt++) { accL[mt][nt] = 0; accH[mt][nt] = 0; }

    i32x4 Ab[2][MT][2], Bb[2][NT];
    #pragma unroll
    for (int nt = 0; nt < NT; nt++) Bb[0][nt] = *(const i32x4*)(bp[nt]);
    #pragma unroll
    for (int mt = 0; mt < MT; mt++) {
        const int p = pb[mt];
        const int ao = p * 64 + (((kg + (p >> 1)) & 3) << 4);
        Ab[0][mt][0] = *(const i32x4*)&X[ao];
        Ab[0][mt][1] = *(const i32x4*)&X[CH8 * PSTR + ao];
    }

    #pragma unroll 2
    for (int it = 0; it < NITER; ++it) {
        const int cur = it & 1, nxt = cur ^ 1;
        if (it + 1 < NITER) {
            const int it1 = it + 1;
            const int tap = it1 / CH8, ch = it1 % CH8;
            const int dtap = (tap / 3) * COLS + (tap % 3);
            const int woff = tap * CO * CI + ch * 64;
            #pragma unroll
            for (int nt = 0; nt < NT; nt++)
                Bb[nxt][nt] = *(const i32x4*)(bp[nt] + woff);
            #pragma unroll
            for (int mt = 0; mt < MT; mt++) {
                const int p = pb[mt] + dtap;
                const int ao = p * 64 + (((kg + (p >> 1)) & 3) << 4);
                Ab[nxt][mt][0] = *(const i32x4*)&X[ch * PSTR + ao];
                Ab[nxt][mt][1] = *(const i32x4*)&X[(CH8 + ch) * PSTR + ao];
            }
        }
        #pragma unroll
        for (int mt = 0; mt < MT; mt++)
            #pragma unroll
            for (int nt = 0; nt < NT; nt++) {
                accL[mt][nt] = __builtin_amdgcn_mfma_i32_16x16x64_i8(
                    Ab[cur][mt][0], Bb[cur][nt], accL[mt][nt], 0, 0, 0);
                accH[mt][nt] = __builtin_amdgcn_mfma_i32_16x16x64_i8(
                    Ab[cur][mt][1], Bb[cur][nt], accH[mt][nt], 0, 0, 0);
            }
    }

    // epilogue: sum = 256*accH + accL (exact i32); pool in int; dq + bias + relu
    const double c2 = scr[2];
    const float alpha = (float)(scr[1] / (c2 > 1.0 ? c2 : 1.0));
    const float dq = alpha / S;
    float tmax = 0.f;
    #pragma unroll
    for (int mt = 0; mt < MT; mt++) {
        const int pp = (wm * MT + mt) * 4 + kg;
        const int lph = pp / PO, lpw = pp % PO;
        const int gpp = (hb * POR + lph) * PO + lpw;
        unsigned short* yr = yout + ((long)bimg * (PO * PO) + gpp) * (2 * CO);
        #pragma unroll
        for (int nt = 0; nt < NT; nt++) {
            const int co = co0 + (wn * NT + nt) * 16 + lm;
            const i32x4 aL = accL[mt][nt], aH = accH[mt][nt];
            int s0 = aH[0] * 256 + aL[0];
            int s1 = aH[1] * 256 + aL[1];
            int s2 = aH[2] * 256 + aL[2];
            int s3 = aH[3] * 256 + aL[3];
            int sm = s0 > s1 ? s0 : s1;
            int sn = s2 > s3 ? s2 : s3;
            sm = sm > sn ? sm : sn;
            float o = fmaxf(dq * (float)sm + bias[co], 0.f);
            tmax = fmaxf(tmax, o);
            unsigned short hi = f2bf(o);
            unsigned short lo = f2bf(o - bf2f(hi));
            yr[co] = hi;
            yr[CO + co] = lo;
        }
    }
    if (amax_out) {
        #pragma unroll
        for (int off = 32; off > 0; off >>= 1)
            tmax = fmaxf(tmax, __shfl_down(tmax, off, 64));
        if (lane == 0) redm[wid] = tmax;
        __syncthreads();
        if (tid == 0) {
            float m = fmaxf(fmaxf(redm[0], redm[1]), fmaxf(redm[2], redm[3]));
            atomicMax(amax_out, __float_as_int(m));
        }
    }
}

// ---------------------------------------------------------------------------
// fc1 MFMA (bf16, unchanged): K=8192 hi/lo slots, split-K, reg-pipelined.
// ---------------------------------------------------------------------------
template <int S>
__global__ __launch_bounds__(256) void fc1_mfma(
        const unsigned short* __restrict__ A,
        const unsigned short* __restrict__ Bw,
        float* __restrict__ parts) {
    constexpr int KCH = 8192 / S;
    constexpr int NSTEP = KCH / 32;
    const int m0 = blockIdx.x * 128;
    const int n0 = blockIdx.y * 128;
    const int s = blockIdx.z;
    const int tid = threadIdx.x;
    const int lane = tid & 63, wid = tid >> 6;
    const int wm = wid >> 1, wn = wid & 1;
    const int lm = lane & 15, kg = lane >> 4;

    const long k0 = (long)s * KCH + kg * 8;
    const unsigned short* ap[4];
    const unsigned short* bp[4];
    #pragma unroll
    for (int t = 0; t < 4; t++) {
        ap[t] = A + (long)(m0 + wm * 64 + t * 16 + lm) * 8192 + k0;
        bp[t] = Bw + (long)(n0 + wn * 64 + t * 16 + lm) * 8192 + k0;
    }

    f32x4 acc[4][4] = {};
    short8 Ab[2][4], Bb[2][4];
    #pragma unroll
    for (int t = 0; t < 4; t++) {
        Ab[0][t] = *(const short8*)(ap[t]);
        Bb[0][t] = *(const short8*)(bp[t]);
    }

    #pragma unroll 2
    for (int st = 0; st < NSTEP; ++st) {
        const int cur = st & 1, nxt = cur ^ 1;
        if (st + 1 < NSTEP) {
            const int off = (st + 1) * 32;
            #pragma unroll
            for (int t = 0; t < 4; t++) {
                Ab[nxt][t] = *(const short8*)(ap[t] + off);
                Bb[nxt][t] = *(const short8*)(bp[t] + off);
            }
        }
        #pragma unroll
        for (int mt = 0; mt < 4; mt++)
            #pragma unroll
            for (int nt = 0; nt < 4; nt++)
                acc[mt][nt] = __builtin_amdgcn_mfma_f32_16x16x32_bf16(
                    Ab[cur][mt], Bb[cur][nt], acc[mt][nt], 0, 0, 0);
    }

    #pragma unroll
    for (int mt = 0; mt < 4; mt++) {
        #pragma unroll
        for (int r = 0; r < 4; r++) {
            const int b = m0 + wm * 64 + mt * 16 + kg * 4 + r;
            #pragma unroll
            for (int nt = 0; nt < 4; nt++) {
                const int j = n0 + wn * 64 + nt * 16 + lm;
                parts[((long)s * 1024 + b) * 256 + j] = acc[mt][nt][r];
            }
        }
    }
}

template <int S>
__global__ void fc1_reduce(const float* __restrict__ parts,
                           const double* __restrict__ scr,
                           const float* __restrict__ bias,
                           float* __restrict__ f1) {
    const int idx = blockIdx.x * blockDim.x + threadIdx.x;  // < 262144
    const int j = idx & 255;
    float s = 0.f;
    #pragma unroll
    for (int p = 0; p < S; p++) s += parts[(long)p * 262144 + idx];
    const double c2 = scr[2];
    const float alpha = (float)(scr[1] / (c2 > 1.0 ? c2 : 1.0));
    f1[idx] = fmaxf(alpha * s + bias[j], 0.f);
}

__global__ void fc2_kernel(const float* __restrict__ a,
                           const float* __restrict__ wt,
                           const float* __restrict__ bias,
                           float* __restrict__ out, int B) {
    const int idx = blockIdx.x * blockDim.x + threadIdx.x;
    if (idx >= B * 10) return;
    const int k = idx % 10;
    const int b = idx / 10;
    const float* ar = a + (long)b * 256;
    const float* wr = wt + (long)k * 256;
    float acc = 0.f;
    #pragma unroll 4
    for (int i = 0; i < 256; i++) acc += ar[i] * wr[i];
    out[idx] = acc + bias[k];
}

extern "C" void kernel_launch(void* const* d_in, const int* in_sizes, int n_in,
                              void* d_out, int out_size, void* d_ws, size_t ws_size,
                              hipStream_t stream) {
    const float* x   = (const float*)d_in[0];
    const float* w1  = (const float*)d_in[1];
    const float* b1  = (const float*)d_in[2];
    const float* w2  = (const float*)d_in[3];
    const float* b2  = (const float*)d_in[4];
    const float* w3  = (const float*)d_in[5];
    const float* b3  = (const float*)d_in[6];
    const float* wf1 = (const float*)d_in[7];
    const float* bf1 = (const float*)d_in[8];
    const float* wf2 = (const float*)d_in[9];
    const float* bf2 = (const float*)d_in[10];
    float* out = (float*)d_out;
    float* ws = (float*)d_ws;

    const int B = 1024;

    float*          wt1   = ws + WS_WT1;
    signed char*    w2p8  = (signed char*)(ws + WS_W2P);
    signed char*    w3p8  = (signed char*)(ws + WS_W3P);
    unsigned short* wtf1b = (unsigned short*)(ws + WS_WTF1);
    float*          wtf2  = ws + WS_WTF2;
    float*          a1f   = ws + WS_A1;
    unsigned short* a2p   = (unsigned short*)(ws + WS_A2);
    unsigned short* a3p   = (unsigned short*)(ws + WS_A3);
    float*          f1    = ws + WS_F1;
    double*         scr   = (double*)(ws + WS_SCR);
    int*            amax1 = (int*)(scr + 20);
    int*            amax2 = amax1 + 1;
    float*          parts = ws + WS_A1;   // alias: a1 dead after conv2

    hipMemsetAsync(scr, 0, 22 * sizeof(double), stream);

    TernArgs ta;
    ta.w[0] = w1;  ta.n[0] = N_WT1;
    ta.w[1] = w2;  ta.n[1] = 128 * 64 * 9;
    ta.w[2] = w3;  ta.n[2] = 256 * 128 * 9;
    ta.w[3] = wf1; ta.n[3] = 256 * 4096;
    ta.w[4] = wf2; ta.n[4] = 10 * 256;

    hipLaunchKernelGGL(tern_stats1, dim3(128, 5), dim3(256), 0, stream, ta, scr);
    hipLaunchKernelGGL(tern_stats2, dim3(128, 5), dim3(256), 0, stream, ta, scr);
    hipLaunchKernelGGL(tern_write_all, dim3(128, 5), dim3(256), 0, stream,
                       ta, scr, wt1, w2p8, w3p8, wtf1b, wtf2);

    // conv1: quadrant-tiled fp32 direct -> a1 fp32 rows + amax1
    hipLaunchKernelGGL(conv1_q, dim3(B * 4), dim3(256), 0, stream,
                       x, wt1, b1, a1f, amax1);

    // conv2: CI=64, HI=16, CO=128, HB=4, fp32 input -> 4096 blocks, i8 MFMA
    hipLaunchKernelGGL((conv_i8<64, 16, 128, 4, 1, true>), dim3(B * 4, 1),
                       dim3(256), 0, stream, a1f, w2p8, b2, scr + 4, amax1,
                       amax2, a2p);

    // conv3: CI=128, HI=8, CO=256, HB=1, 2 co-halves, bf16-pair input
    hipLaunchKernelGGL((conv_i8<128, 8, 256, 1, 2, false>), dim3(B, 2),
                       dim3(256), 0, stream, a2p, w3p8, b3, scr + 8, amax2,
                       (int*)nullptr, a3p);

    // fc1: MFMA split-K + reduce(alpha+bias+relu)
    hipLaunchKernelGGL((fc1_mfma<FC1_S>), dim3(8, 2, FC1_S), dim3(256), 0, stream,
                       a3p, wtf1b, parts);
    hipLaunchKernelGGL((fc1_reduce<FC1_S>), dim3(1024), dim3(256), 0, stream,
                       parts, scr + 12, bf1, f1);

    // fc2
    hipLaunchKernelGGL(fc2_kernel, dim3((B * 10 + 255) / 256), dim3(256), 0,
                       stream, f1, wtf2, bf2, out, B);
}

// Round 11
// 322.990 us; speedup vs baseline: 1.2616x; 1.1458x over previous
//
#include <hip/hip_runtime.h>
#include <hip/hip_bf16.h>

// ---------------------------------------------------------------------------
// TernaryCIFAR10Net on MI355X — Round 11: R10 with the conv2 output-stride
// bug fixed (bimg * PO*PO, NOT * HB — PO*PO is already the full pooled image).
//   unified i8 conv template:
//     - conv3: one block = one image x ALL 256 co (WM=1/WN=4)
//     - conv2: HB=2, WM=2/WN=2 (M=128)
//     - staging: exactly 5 trips, fully unrolled, loads batched up front
//     - A-fragments: both planes' 8 ds_read_b128 before the 32 MFMAs
//     - B double-buffered from L2
//   conv1 (quadrant fp32 direct), fc1 (bf16 MFMA split-K), fc2, ternarize
//   unchanged.
// ---------------------------------------------------------------------------

typedef __attribute__((ext_vector_type(8))) short short8;
typedef __attribute__((ext_vector_type(4))) float f32x4;
typedef __attribute__((ext_vector_type(4))) int i32x4;

__device__ __forceinline__ unsigned short f2bf(float x) {
    unsigned u = __float_as_uint(x);
    return (unsigned short)((u + 0x7fffu + ((u >> 16) & 1u)) >> 16);  // RNE
}
__device__ __forceinline__ float bf2f(unsigned short b) {
    return __uint_as_float(((unsigned)b) << 16);
}

// workspace layout (4-byte units)
#define WS_WT1   0
#define N_WT1    (64*3*3*3)
#define WS_W2P   (WS_WT1 + N_WT1)
#define N_W2P    (9*128*64)
#define WS_W3P   (WS_W2P + N_W2P)
#define N_W3P    (9*256*128)
#define WS_WTF1  (WS_W3P + N_W3P)
#define N_WTF1   (256*4096)            // ushort signs [256][8192]
#define WS_WTF2  (WS_WTF1 + N_WTF1)
#define N_WTF2   (10*256)
#define WS_A1    (WS_WTF2 + N_WTF2)
#define N_A1     (1024*256*64)         // a1: [B][256px][64 fp32]; parts alias
#define WS_A2    (WS_A1 + N_A1)
#define N_A2     (1024*64*128)         // a2: [B][64px][256 ushort] (hi/lo bf16)
#define WS_A3    (WS_A2 + N_A2)
#define N_A3     (1024*16*256)         // a3: [B][16px][512 ushort]
#define WS_F1    (WS_A3 + N_A3)
#define N_F1     (1024*256)
#define WS_SCR   (WS_F1 + N_F1)

#define FC1_S    16

struct TernArgs {
    const float* w[5];
    int n[5];
};

// ---------------------------------------------------------------------------
// Ternarize stats (fused over 5 weights): scr[wi] = {sum|w|, msum, count, pad}
// ---------------------------------------------------------------------------
__global__ void tern_stats1(TernArgs ta, double* __restrict__ scr) {
    const int wi = blockIdx.y;
    const float* __restrict__ w = ta.w[wi];
    const int n = ta.n[wi];
    double s = 0.0;
    for (int i = blockIdx.x * blockDim.x + threadIdx.x; i < n;
         i += gridDim.x * blockDim.x)
        s += (double)fabsf(w[i]);
    #pragma unroll
    for (int off = 32; off > 0; off >>= 1) s += __shfl_down(s, off, 64);
    __shared__ double red[4];
    const int lane = threadIdx.x & 63, wv = threadIdx.x >> 6;
    if (lane == 0) red[wv] = s;
    __syncthreads();
    if (threadIdx.x == 0)
        atomicAdd(scr + wi * 4, red[0] + red[1] + red[2] + red[3]);
}

__global__ void tern_stats2(TernArgs ta, double* __restrict__ scr) {
    const int wi = blockIdx.y;
    const float* __restrict__ w = ta.w[wi];
    const int n = ta.n[wi];
    const float delta = (float)(0.7 * scr[wi * 4] / (double)n);
    double ms = 0.0, cnt = 0.0;
    for (int i = blockIdx.x * blockDim.x + threadIdx.x; i < n;
         i += gridDim.x * blockDim.x) {
        float a = fabsf(w[i]);
        if (a > delta) { ms += (double)a; cnt += 1.0; }
    }
    #pragma unroll
    for (int off = 32; off > 0; off >>= 1) {
        ms += __shfl_down(ms, off, 64);
        cnt += __shfl_down(cnt, off, 64);
    }
    __shared__ double redm[4], redc[4];
    const int lane = threadIdx.x & 63, wv = threadIdx.x >> 6;
    if (lane == 0) { redm[wv] = ms; redc[wv] = cnt; }
    __syncthreads();
    if (threadIdx.x == 0) {
        atomicAdd(scr + wi * 4 + 1, redm[0] + redm[1] + redm[2] + redm[3]);
        atomicAdd(scr + wi * 4 + 2, redc[0] + redc[1] + redc[2] + redc[3]);
    }
}

// ---------------------------------------------------------------------------
// Fused writer.
// ---------------------------------------------------------------------------
__global__ void tern_write_all(TernArgs ta, const double* __restrict__ scr,
                               float* __restrict__ wt1,
                               signed char* __restrict__ w2p8,
                               signed char* __restrict__ w3p8,
                               unsigned short* __restrict__ wtf1b,
                               float* __restrict__ wtf2) {
    const int wi = blockIdx.y;
    const float* __restrict__ w = ta.w[wi];
    const int n = ta.n[wi];
    const double* sc = scr + wi * 4;
    const float delta = (float)(0.7 * sc[0] / (double)n);
    const int i0 = blockIdx.x * blockDim.x + threadIdx.x;
    const int stride = gridDim.x * blockDim.x;

    if (wi == 0 || wi == 4) {
        const double c = sc[2];
        const float alpha = (float)(sc[1] / (c > 1.0 ? c : 1.0));
        float* dst = (wi == 0) ? wt1 : wtf2;
        for (int i = i0; i < n; i += stride) {
            float v = w[i];
            dst[i] = (fabsf(v) > delta) ? (v > 0.0f ? alpha : -alpha) : 0.0f;
        }
    } else if (wi == 1 || wi == 2) {
        const int CIc = (wi == 1) ? 64 : 128;
        const int COc = (wi == 1) ? 128 : 256;
        signed char* dst = (wi == 1) ? w2p8 : w3p8;
        for (int i = i0; i < n; i += stride) {
            const int co = i / (CIc * 9);
            const int r = i % (CIc * 9);
            const int ci = r / 9, tap = r % 9;
            float v = w[i];
            signed char s = (fabsf(v) > delta) ? (v > 0.0f ? 1 : -1) : 0;
            dst[(tap * COc + co) * CIc + ci] = s;
        }
    } else {  // wi == 3: fc1 signs, hi and lo slots
        for (int i = i0; i < n; i += stride) {
            const int j = i >> 12;
            const int k = i & 4095;
            const int c = k >> 4, px = k & 15;
            float v = w[i];
            unsigned short s = (fabsf(v) > delta) ? (v > 0.0f ? 0x3f80 : 0xbf80) : 0;
            unsigned short* row = wtf1b + ((long)j << 13) + px * 512 + c;
            row[0] = s;
            row[256] = s;
        }
    }
}

// ---------------------------------------------------------------------------
// conv1: block = (img, quadrant); weights [ci][tap][co] co-minor.
// ---------------------------------------------------------------------------
__global__ __launch_bounds__(256) void conv1_q(
        const float* __restrict__ x, const float* __restrict__ wt,
        const float* __restrict__ bias, float* __restrict__ y,
        int* __restrict__ amax) {
    constexpr int HI = 32, CI = 3, CO = 64, PO = 16;
    constexpr int PP = 20;
    __shared__ float patch[CI * 18 * PP];
    __shared__ float sw[CI * 9 * CO];
    __shared__ float redm[4];

    const int b = blockIdx.x >> 2;
    const int quad = blockIdx.x & 3;
    const int tid = threadIdx.x;

    for (int i = tid; i < CO * CI * 9; i += 256) {
        const int co = i / 27;
        const int r = i % 27;
        sw[r * CO + co] = wt[i];
    }
    const int qh = (quad >> 1) * 16, qw = (quad & 1) * 16;
    for (int i = tid; i < CI * 18 * 18; i += 256) {
        const int ci = i / 324;
        const int r = (i % 324) / 18;
        const int c = i % 18;
        const int h = qh - 1 + r, w = qw - 1 + c;
        float v = 0.f;
        if ((unsigned)h < (unsigned)HI && (unsigned)w < (unsigned)HI)
            v = x[(((long)b * CI + ci) * HI + h) * HI + w];
        patch[(ci * 18 + r) * PP + c] = v;
    }
    __syncthreads();

    const int pxq = tid >> 2;
    const int cg = tid & 3;
    const int lph = pxq >> 3, lpw = pxq & 7;

    float acc[16][4];
    #pragma unroll
    for (int c = 0; c < 16; c++)
        #pragma unroll
        for (int q = 0; q < 4; q++) acc[c][q] = 0.f;

    for (int ci = 0; ci < CI; ci++) {
        float p[4][4];
        #pragma unroll
        for (int r = 0; r < 4; r++)
            #pragma unroll
            for (int c = 0; c < 4; c++)
                p[r][c] = patch[(ci * 18 + 2 * lph + r) * PP + 2 * lpw + c];
        #pragma unroll
        for (int kh = 0; kh < 3; kh++)
            #pragma unroll
            for (int kw = 0; kw < 3; kw++) {
                const float4* wv = (const float4*)
                    &sw[((ci * 3 + kh) * 3 + kw) * CO + cg * 16];
                const float4 w0 = wv[0], w1 = wv[1], w2 = wv[2], w3 = wv[3];
                const float w16[16] = {w0.x, w0.y, w0.z, w0.w,
                                       w1.x, w1.y, w1.z, w1.w,
                                       w2.x, w2.y, w2.z, w2.w,
                                       w3.x, w3.y, w3.z, w3.w};
                const float p00 = p[kh][kw], p01 = p[kh][kw + 1];
                const float p10 = p[kh + 1][kw], p11 = p[kh + 1][kw + 1];
                #pragma unroll
                for (int c = 0; c < 16; c++) {
                    const float wvv = w16[c];
                    acc[c][0] += wvv * p00;
                    acc[c][1] += wvv * p01;
                    acc[c][2] += wvv * p10;
                    acc[c][3] += wvv * p11;
                }
            }
    }

    const int gpx = ((quad >> 1) * 8 + lph) * PO + (quad & 1) * 8 + lpw;
    float* yr = y + ((long)b * 256 + gpx) * CO + cg * 16;
    float tmax = 0.f;
    #pragma unroll
    for (int c = 0; c < 16; c++) {
        float m = fmaxf(fmaxf(acc[c][0], acc[c][1]), fmaxf(acc[c][2], acc[c][3]));
        float o = fmaxf(m + bias[cg * 16 + c], 0.f);
        tmax = fmaxf(tmax, o);
        yr[c] = o;
    }
    #pragma unroll
    for (int off = 32; off > 0; off >>= 1)
        tmax = fmaxf(tmax, __shfl_down(tmax, off, 64));
    const int lane = tid & 63, wv2 = tid >> 6;
    if (lane == 0) redm[wv2] = tmax;
    __syncthreads();
    if (tid == 0) {
        float m = fmaxf(fmaxf(redm[0], redm[1]), fmaxf(redm[2], redm[3]));
        atomicMax(amax, __float_as_int(m));
    }
}

// ---------------------------------------------------------------------------
// int8 MFMA conv. WM x WN wave grid (WM*WN == 4), MT=NT=4.
// M = WM*64 pixels (= all pixels of the h-slab), N = WN*64 = CO.
// ---------------------------------------------------------------------------
template <int CI, int HI, int CO, int HB, int WM, int WN, bool INF32>
__global__ __launch_bounds__(256) void conv_i8(
        const void* __restrict__ xin,
        const signed char* __restrict__ wp,     // [9][CO][CI] int8 signs
        const float* __restrict__ bias,
        const double* __restrict__ scr,         // layer {_, msum, count}
        const int* __restrict__ amax_in,
        int* __restrict__ amax_out,             // nullptr if unused
        unsigned short* __restrict__ yout) {
    constexpr int CH8 = CI / 64;
    constexpr int NITER = 9 * CH8;
    constexpr int HR = HI / HB;
    constexpr int ROWS = HR + 2;
    constexpr int COLS = HI + 2;
    constexpr int NPIX = ROWS * COLS;
    constexpr int PSTR = NPIX * 64 + 32;    // bytes per g-plane
    constexpr int PO = HI / 2;
    constexpr int POR = HR / 2;
    constexpr int MT = 4, NT = 4;
    constexpr int NST = ROWS * HI * (CI / 8) / 256;
    static_assert(WM * WN == 4, "4 waves");
    static_assert(WM * 64 == HR * HI, "M covers slab pixels");
    static_assert(WN * 64 == CO, "N covers all co");
    static_assert(NST * 256 == ROWS * HI * (CI / 8), "exact staging trips");

    __shared__ __align__(16) char X[2 * CH8 * PSTR];
    __shared__ float redm[4];

    const int bimg = blockIdx.x / HB;
    const int hb = blockIdx.x % HB;
    const int tid = threadIdx.x;

    const float S = 32512.0f / fmaxf(__int_as_float(*amax_in), 1e-30f);

    // halo zero (borders only; disjoint from interior staging)
    constexpr int HALO = 2 * COLS + 2 * (ROWS - 2);
    for (int i = tid; i < HALO * 2 * CH8 * 4; i += 256) {
        const int u = i & 3;
        const int t = i >> 2;
        const int g = t % (2 * CH8);
        const int hp = t / (2 * CH8);
        int p;
        if (hp < COLS) p = hp;
        else if (hp < 2 * COLS) p = (ROWS - 1) * COLS + (hp - COLS);
        else {
            const int e = hp - 2 * COLS;
            p = (1 + (e >> 1)) * COLS + ((e & 1) ? (COLS - 1) : 0);
        }
        *(int4*)&X[g * PSTR + p * 64 + u * 16] = make_int4(0, 0, 0, 0);
    }

    // ---- staging phase 1: batch all global loads ----
    uint4 va[NST], vb[NST];
    bool val[NST];
    int pidx[NST], cbase[NST];
    #pragma unroll
    for (int s2 = 0; s2 < NST; s2++) {
        const int i = tid + s2 * 256;
        const int q8 = i % (CI / 8);
        const int t = i / (CI / 8);
        const int c = t % HI;
        const int r = t / HI;
        const int h = hb * HR + r - 1;
        val[s2] = (unsigned)h < (unsigned)HI;
        pidx[s2] = r * COLS + c + 1;
        cbase[s2] = q8 * 8;
        if (val[s2]) {
            if (INF32) {
                const float* pxr = (const float*)xin +
                    ((long)(bimg * HI + h) * HI + c) * CI + q8 * 8;
                va[s2] = *(const uint4*)(pxr);
                vb[s2] = *(const uint4*)(pxr + 4);
            } else {
                const unsigned short* pxr = (const unsigned short*)xin +
                    ((long)(bimg * HI + h) * HI + c) * (2 * CI);
                va[s2] = *(const uint4*)(pxr + q8 * 8);
                vb[s2] = *(const uint4*)(pxr + CI + q8 * 8);
            }
        }
    }
    // ---- staging phase 2: quantize + LDS store ----
    #pragma unroll
    for (int s2 = 0; s2 < NST; s2++) {
        if (!val[s2]) continue;
        float f[8];
        if (INF32) {
            const float* fa = (const float*)&va[s2];
            const float* fb = (const float*)&vb[s2];
            #pragma unroll
            for (int j = 0; j < 4; j++) { f[j] = fa[j]; f[4 + j] = fb[j]; }
        } else {
            const unsigned* hw = (const unsigned*)&va[s2];
            const unsigned* lw = (const unsigned*)&vb[s2];
            #pragma unroll
            for (int j = 0; j < 8; j++) {
                const unsigned hu = (j & 1) ? (hw[j >> 1] >> 16)
                                            : (hw[j >> 1] & 0xffffu);
                const unsigned lu = (j & 1) ? (lw[j >> 1] >> 16)
                                            : (lw[j >> 1] & 0xffffu);
                f[j] = __uint_as_float(hu << 16) + __uint_as_float(lu << 16);
            }
        }
        unsigned pl0 = 0, pl1 = 0, ph0 = 0, ph1 = 0;
        #pragma unroll
        for (int j = 0; j < 8; j++) {
            const int qi = (int)(f[j] * S + 0.5f);
            const int ql = (qi << 24) >> 24;
            const int qh = (qi - ql) >> 8;
            const int sh = (j & 3) * 8;
            if (j < 4) {
                pl0 |= (unsigned)(ql & 255) << sh;
                ph0 |= (unsigned)(qh & 255) << sh;
            } else {
                pl1 |= (unsigned)(ql & 255) << sh;
                ph1 |= (unsigned)(qh & 255) << sh;
            }
        }
        const int p = pidx[s2];
        const int ch = cbase[s2] >> 6;
        const int cc = cbase[s2] & 63;
        const int slot = ((cc >> 4) + (p >> 1)) & 3;
        const int base = p * 64 + slot * 16 + (cc & 15);
        *(uint2*)&X[ch * PSTR + base] = make_uint2(pl0, pl1);
        *(uint2*)&X[(CH8 + ch) * PSTR + base] = make_uint2(ph0, ph1);
    }
    __syncthreads();

    const int lane = tid & 63;
    const int wid = tid >> 6;
    const int wm = (WM == 1) ? 0 : (wid >> 1);
    const int wn = (WM == 1) ? wid : (wid & 1);
    const int lm = lane & 15;
    const int kg = lane >> 4;

    int pb[MT];
    #pragma unroll
    for (int mt = 0; mt < MT; mt++) {
        const int m = (wm * MT + mt) * 16 + lm;
        const int pp = m >> 2, sub = m & 3;
        const int lph = pp / PO, lpw = pp % PO;
        const int h = 2 * lph + (sub >> 1);
        const int w = 2 * lpw + (sub & 1);
        pb[mt] = h * COLS + w;
    }
    const signed char* bp[NT];
    #pragma unroll
    for (int nt = 0; nt < NT; nt++) {
        const int co = (wn * NT + nt) * 16 + lm;
        bp[nt] = wp + (long)co * CI + kg * 16;
    }

    i32x4 accL[MT][NT], accH[MT][NT];
    #pragma unroll
    for (int mt = 0; mt < MT; mt++)
        #pragma unroll
        for (int nt = 0; nt < NT; nt++) { accL[mt][nt] = 0; accH[mt][nt] = 0; }

    i32x4 Bb[2][NT];
    #pragma unroll
    for (int nt = 0; nt < NT; nt++) Bb[0][nt] = *(const i32x4*)(bp[nt]);

    #pragma unroll 2
    for (int it = 0; it < NITER; ++it) {
        const int cur = it & 1, nxt = cur ^ 1;
        if (it + 1 < NITER) {
            const int it1 = it + 1;
            const int tap = it1 / CH8, ch1 = it1 % CH8;
            const int woff = tap * CO * CI + ch1 * 64;
            #pragma unroll
            for (int nt = 0; nt < NT; nt++)
                Bb[nxt][nt] = *(const i32x4*)(bp[nt] + woff);
        }
        const int tap = it / CH8, ch = it % CH8;
        const int dtap = (tap / 3) * COLS + (tap % 3);
        i32x4 Af0[MT], Af1[MT];
        #pragma unroll
        for (int mt = 0; mt < MT; mt++) {
            const int p = pb[mt] + dtap;
            const int ao = p * 64 + (((kg + (p >> 1)) & 3) << 4);
            Af0[mt] = *(const i32x4*)&X[ch * PSTR + ao];
            Af1[mt] = *(const i32x4*)&X[(CH8 + ch) * PSTR + ao];
        }
        #pragma unroll
        for (int mt = 0; mt < MT; mt++)
            #pragma unroll
            for (int nt = 0; nt < NT; nt++)
                accL[mt][nt] = __builtin_amdgcn_mfma_i32_16x16x64_i8(
                    Af0[mt], Bb[cur][nt], accL[mt][nt], 0, 0, 0);
        #pragma unroll
        for (int mt = 0; mt < MT; mt++)
            #pragma unroll
            for (int nt = 0; nt < NT; nt++)
                accH[mt][nt] = __builtin_amdgcn_mfma_i32_16x16x64_i8(
                    Af1[mt], Bb[cur][nt], accH[mt][nt], 0, 0, 0);
    }

    // epilogue: sum = 256*accH + accL (exact i32); pool in int; dq + bias + relu
    const double c2 = scr[2];
    const float alpha = (float)(scr[1] / (c2 > 1.0 ? c2 : 1.0));
    const float dq = alpha / S;
    float tmax = 0.f;
    #pragma unroll
    for (int mt = 0; mt < MT; mt++) {
        const int pp = (wm * MT + mt) * 4 + kg;
        const int lph = pp / PO, lpw = pp % PO;
        const int gpp = (hb * POR + lph) * PO + lpw;
        // NOTE: per-image pooled pixel count is PO*PO (full image), NOT *HB.
        unsigned short* yr = yout + ((long)bimg * (PO * PO) + gpp) * (2 * CO);
        #pragma unroll
        for (int nt = 0; nt < NT; nt++) {
            const int co = (wn * NT + nt) * 16 + lm;
            const i32x4 aL = accL[mt][nt], aH = accH[mt][nt];
            int s0 = aH[0] * 256 + aL[0];
            int s1 = aH[1] * 256 + aL[1];
            int s2 = aH[2] * 256 + aL[2];
            int s3 = aH[3] * 256 + aL[3];
            int sm = s0 > s1 ? s0 : s1;
            int sn = s2 > s3 ? s2 : s3;
            sm = sm > sn ? sm : sn;
            float o = fmaxf(dq * (float)sm + bias[co], 0.f);
            tmax = fmaxf(tmax, o);
            unsigned short hi = f2bf(o);
            unsigned short lo = f2bf(o - bf2f(hi));
            yr[co] = hi;
            yr[CO + co] = lo;
        }
    }
    if (amax_out) {
        #pragma unroll
        for (int off = 32; off > 0; off >>= 1)
            tmax = fmaxf(tmax, __shfl_down(tmax, off, 64));
        if (lane == 0) redm[wid] = tmax;
        __syncthreads();
        if (tid == 0) {
            float m = fmaxf(fmaxf(redm[0], redm[1]), fmaxf(redm[2], redm[3]));
            atomicMax(amax_out, __float_as_int(m));
        }
    }
}

// ---------------------------------------------------------------------------
// fc1 MFMA (bf16): K=8192 hi/lo slots, split-K, reg-pipelined.
// ---------------------------------------------------------------------------
template <int S>
__global__ __launch_bounds__(256) void fc1_mfma(
        const unsigned short* __restrict__ A,
        const unsigned short* __restrict__ Bw,
        float* __restrict__ parts) {
    constexpr int KCH = 8192 / S;
    constexpr int NSTEP = KCH / 32;
    const int m0 = blockIdx.x * 128;
    const int n0 = blockIdx.y * 128;
    const int s = blockIdx.z;
    const int tid = threadIdx.x;
    const int lane = tid & 63, wid = tid >> 6;
    const int wm = wid >> 1, wn = wid & 1;
    const int lm = lane & 15, kg = lane >> 4;

    const long k0 = (long)s * KCH + kg * 8;
    const unsigned short* ap[4];
    const unsigned short* bp[4];
    #pragma unroll
    for (int t = 0; t < 4; t++) {
        ap[t] = A + (long)(m0 + wm * 64 + t * 16 + lm) * 8192 + k0;
        bp[t] = Bw + (long)(n0 + wn * 64 + t * 16 + lm) * 8192 + k0;
    }

    f32x4 acc[4][4] = {};
    short8 Ab[2][4], Bb[2][4];
    #pragma unroll
    for (int t = 0; t < 4; t++) {
        Ab[0][t] = *(const short8*)(ap[t]);
        Bb[0][t] = *(const short8*)(bp[t]);
    }

    #pragma unroll 2
    for (int st = 0; st < NSTEP; ++st) {
        const int cur = st & 1, nxt = cur ^ 1;
        if (st + 1 < NSTEP) {
            const int off = (st + 1) * 32;
            #pragma unroll
            for (int t = 0; t < 4; t++) {
                Ab[nxt][t] = *(const short8*)(ap[t] + off);
                Bb[nxt][t] = *(const short8*)(bp[t] + off);
            }
        }
        #pragma unroll
        for (int mt = 0; mt < 4; mt++)
            #pragma unroll
            for (int nt = 0; nt < 4; nt++)
                acc[mt][nt] = __builtin_amdgcn_mfma_f32_16x16x32_bf16(
                    Ab[cur][mt], Bb[cur][nt], acc[mt][nt], 0, 0, 0);
    }

    #pragma unroll
    for (int mt = 0; mt < 4; mt++) {
        #pragma unroll
        for (int r = 0; r < 4; r++) {
            const int b = m0 + wm * 64 + mt * 16 + kg * 4 + r;
            #pragma unroll
            for (int nt = 0; nt < 4; nt++) {
                const int j = n0 + wn * 64 + nt * 16 + lm;
                parts[((long)s * 1024 + b) * 256 + j] = acc[mt][nt][r];
            }
        }
    }
}

template <int S>
__global__ void fc1_reduce(const float* __restrict__ parts,
                           const double* __restrict__ scr,
                           const float* __restrict__ bias,
                           float* __restrict__ f1) {
    const int idx = blockIdx.x * blockDim.x + threadIdx.x;  // < 262144
    const int j = idx & 255;
    float s = 0.f;
    #pragma unroll
    for (int p = 0; p < S; p++) s += parts[(long)p * 262144 + idx];
    const double c2 = scr[2];
    const float alpha = (float)(scr[1] / (c2 > 1.0 ? c2 : 1.0));
    f1[idx] = fmaxf(alpha * s + bias[j], 0.f);
}

__global__ void fc2_kernel(const float* __restrict__ a,
                           const float* __restrict__ wt,
                           const float* __restrict__ bias,
                           float* __restrict__ out, int B) {
    const int idx = blockIdx.x * blockDim.x + threadIdx.x;
    if (idx >= B * 10) return;
    const int k = idx % 10;
    const int b = idx / 10;
    const float* ar = a + (long)b * 256;
    const float* wr = wt + (long)k * 256;
    float acc = 0.f;
    #pragma unroll 4
    for (int i = 0; i < 256; i++) acc += ar[i] * wr[i];
    out[idx] = acc + bias[k];
}

extern "C" void kernel_launch(void* const* d_in, const int* in_sizes, int n_in,
                              void* d_out, int out_size, void* d_ws, size_t ws_size,
                              hipStream_t stream) {
    const float* x   = (const float*)d_in[0];
    const float* w1  = (const float*)d_in[1];
    const float* b1  = (const float*)d_in[2];
    const float* w2  = (const float*)d_in[3];
    const float* b2  = (const float*)d_in[4];
    const float* w3  = (const float*)d_in[5];
    const float* b3  = (const float*)d_in[6];
    const float* wf1 = (const float*)d_in[7];
    const float* bf1 = (const float*)d_in[8];
    const float* wf2 = (const float*)d_in[9];
    const float* bf2 = (const float*)d_in[10];
    float* out = (float*)d_out;
    float* ws = (float*)d_ws;

    const int B = 1024;

    float*          wt1   = ws + WS_WT1;
    signed char*    w2p8  = (signed char*)(ws + WS_W2P);
    signed char*    w3p8  = (signed char*)(ws + WS_W3P);
    unsigned short* wtf1b = (unsigned short*)(ws + WS_WTF1);
    float*          wtf2  = ws + WS_WTF2;
    float*          a1f   = ws + WS_A1;
    unsigned short* a2p   = (unsigned short*)(ws + WS_A2);
    unsigned short* a3p   = (unsigned short*)(ws + WS_A3);
    float*          f1    = ws + WS_F1;
    double*         scr   = (double*)(ws + WS_SCR);
    int*            amax1 = (int*)(scr + 20);
    int*            amax2 = amax1 + 1;
    float*          parts = ws + WS_A1;   // alias: a1 dead after conv2

    hipMemsetAsync(scr, 0, 22 * sizeof(double), stream);

    TernArgs ta;
    ta.w[0] = w1;  ta.n[0] = N_WT1;
    ta.w[1] = w2;  ta.n[1] = 128 * 64 * 9;
    ta.w[2] = w3;  ta.n[2] = 256 * 128 * 9;
    ta.w[3] = wf1; ta.n[3] = 256 * 4096;
    ta.w[4] = wf2; ta.n[4] = 10 * 256;

    hipLaunchKernelGGL(tern_stats1, dim3(128, 5), dim3(256), 0, stream, ta, scr);
    hipLaunchKernelGGL(tern_stats2, dim3(128, 5), dim3(256), 0, stream, ta, scr);
    hipLaunchKernelGGL(tern_write_all, dim3(128, 5), dim3(256), 0, stream,
                       ta, scr, wt1, w2p8, w3p8, wtf1b, wtf2);

    // conv1: quadrant-tiled fp32 direct -> a1 fp32 rows + amax1
    hipLaunchKernelGGL(conv1_q, dim3(B * 4), dim3(256), 0, stream,
                       x, wt1, b1, a1f, amax1);

    // conv2: CI=64, HI=16, CO=128, HB=2, WM=2, WN=2, fp32 input -> 2048 blocks
    hipLaunchKernelGGL((conv_i8<64, 16, 128, 2, 2, 2, true>), dim3(B * 2),
                       dim3(256), 0, stream, a1f, w2p8, b2, scr + 4, amax1,
                       amax2, a2p);

    // conv3: CI=128, HI=8, CO=256, HB=1, WM=1, WN=4 (all co) -> 1024 blocks
    hipLaunchKernelGGL((conv_i8<128, 8, 256, 1, 1, 4, false>), dim3(B),
                       dim3(256), 0, stream, a2p, w3p8, b3, scr + 8, amax2,
                       (int*)nullptr, a3p);

    // fc1: MFMA split-K + reduce(alpha+bias+relu)
    hipLaunchKernelGGL((fc1_mfma<FC1_S>), dim3(8, 2, FC1_S), dim3(256), 0, stream,
                       a3p, wtf1b, parts);
    hipLaunchKernelGGL((fc1_reduce<FC1_S>), dim3(1024), dim3(256), 0, stream,
                       parts, scr + 12, bf1, f1);

    // fc2
    hipLaunchKernelGGL(fc2_kernel, dim3((B * 10 + 255) / 256), dim3(256), 0,
                       stream, f1, wtf2, bf2, out, B);
}

// Round 12
// 307.789 us; speedup vs baseline: 1.3239x; 1.0494x over previous
//
#include <hip/hip_runtime.h>
#include <hip/hip_bf16.h>

// ---------------------------------------------------------------------------
// TernaryCIFAR10Net on MI355X — Round 12:
//   conv1 -> i8 MFMA, K-loop-free: K=64 covers all 27 (ci,tap) twice
//   (ql at k<32, qh at k>=32); two sign matrices BL/BH select the planes;
//   exact sum = 256*accH + accL. Block = 1 image; quantized padded byte
//   planes in LDS; register 2x2 pool; fp32 coalesced out (conv2 unchanged).
//   x amax folded into tern_stats1 (grid.y=6).
//   conv2/conv3 (i8 MFMA), fc1 (bf16 MFMA split-K), fc2 unchanged from R11.
// ---------------------------------------------------------------------------

typedef __attribute__((ext_vector_type(8))) short short8;
typedef __attribute__((ext_vector_type(4))) float f32x4;
typedef __attribute__((ext_vector_type(4))) int i32x4;

__device__ __forceinline__ unsigned short f2bf(float x) {
    unsigned u = __float_as_uint(x);
    return (unsigned short)((u + 0x7fffu + ((u >> 16) & 1u)) >> 16);  // RNE
}
__device__ __forceinline__ float bf2f(unsigned short b) {
    return __uint_as_float(((unsigned)b) << 16);
}

// workspace layout (4-byte units)
#define WS_W1B   0
#define N_W1B    2048                  // 8192 B: [2][64 co][64 k] i8 signs
#define WS_W2P   (WS_W1B + N_W1B)
#define N_W2P    (9*128*64)
#define WS_W3P   (WS_W2P + N_W2P)
#define N_W3P    (9*256*128)
#define WS_WTF1  (WS_W3P + N_W3P)
#define N_WTF1   (256*4096)            // ushort signs [256][8192]
#define WS_WTF2  (WS_WTF1 + N_WTF1)
#define N_WTF2   (10*256)
#define WS_A1    (WS_WTF2 + N_WTF2)
#define N_A1     (1024*256*64)         // a1: [B][256px][64 fp32]; parts alias
#define WS_A2    (WS_A1 + N_A1)
#define N_A2     (1024*64*128)         // a2: [B][64px][256 ushort] (hi/lo bf16)
#define WS_A3    (WS_A2 + N_A2)
#define N_A3     (1024*16*256)         // a3: [B][16px][512 ushort]
#define WS_F1    (WS_A3 + N_A3)
#define N_F1     (1024*256)
#define WS_SCR   (WS_F1 + N_F1)

#define FC1_S    16

struct TernArgs {
    const float* w[6];
    int n[6];
};

// ---------------------------------------------------------------------------
// Stats pass 1: wi<5 -> sum|w| into scr[wi*4]; wi==5 -> amax(x) atomicMax
// into ((int*)(scr+20))[0].
// ---------------------------------------------------------------------------
__global__ void tern_stats1(TernArgs ta, double* __restrict__ scr) {
    const int wi = blockIdx.y;
    const float* __restrict__ w = ta.w[wi];
    const int n = ta.n[wi];
    __shared__ double red[4];
    const int lane = threadIdx.x & 63, wv = threadIdx.x >> 6;
    if (wi == 5) {
        float m = 0.f;
        for (int i = blockIdx.x * blockDim.x + threadIdx.x; i < n;
             i += gridDim.x * blockDim.x)
            m = fmaxf(m, fabsf(w[i]));
        #pragma unroll
        for (int off = 32; off > 0; off >>= 1)
            m = fmaxf(m, __shfl_down(m, off, 64));
        if (lane == 0) red[wv] = (double)m;
        __syncthreads();
        if (threadIdx.x == 0) {
            float mm = (float)fmax(fmax(red[0], red[1]), fmax(red[2], red[3]));
            atomicMax((int*)(scr + 20), __float_as_int(mm));
        }
        return;
    }
    double s = 0.0;
    for (int i = blockIdx.x * blockDim.x + threadIdx.x; i < n;
         i += gridDim.x * blockDim.x)
        s += (double)fabsf(w[i]);
    #pragma unroll
    for (int off = 32; off > 0; off >>= 1) s += __shfl_down(s, off, 64);
    if (lane == 0) red[wv] = s;
    __syncthreads();
    if (threadIdx.x == 0)
        atomicAdd(scr + wi * 4, red[0] + red[1] + red[2] + red[3]);
}

__global__ void tern_stats2(TernArgs ta, double* __restrict__ scr) {
    const int wi = blockIdx.y;
    const float* __restrict__ w = ta.w[wi];
    const int n = ta.n[wi];
    const float delta = (float)(0.7 * scr[wi * 4] / (double)n);
    double ms = 0.0, cnt = 0.0;
    for (int i = blockIdx.x * blockDim.x + threadIdx.x; i < n;
         i += gridDim.x * blockDim.x) {
        float a = fabsf(w[i]);
        if (a > delta) { ms += (double)a; cnt += 1.0; }
    }
    #pragma unroll
    for (int off = 32; off > 0; off >>= 1) {
        ms += __shfl_down(ms, off, 64);
        cnt += __shfl_down(cnt, off, 64);
    }
    __shared__ double redm[4], redc[4];
    const int lane = threadIdx.x & 63, wv = threadIdx.x >> 6;
    if (lane == 0) { redm[wv] = ms; redc[wv] = cnt; }
    __syncthreads();
    if (threadIdx.x == 0) {
        atomicAdd(scr + wi * 4 + 1, redm[0] + redm[1] + redm[2] + redm[3]);
        atomicAdd(scr + wi * 4 + 2, redc[0] + redc[1] + redc[2] + redc[3]);
    }
}

// ---------------------------------------------------------------------------
// Fused writer.
//   0: w1  -> w1b i8 signs [2][64 co][64 k]: BL at k=kp(<27), BH at k=32+kp
//             (w1b pre-zeroed by memset)
//   1: w2  -> w2p8  [tap][co][ci] (CO=128, CI=64)
//   2: w3  -> w3p8  (CO=256, CI=128)
//   3: wf1 -> wtf1b ushort bf16 signs, hi+lo slots
//   4: wf2 -> wtf2 fp32 alpha*sign
// ---------------------------------------------------------------------------
__global__ void tern_write_all(TernArgs ta, const double* __restrict__ scr,
                               signed char* __restrict__ w1b,
                               signed char* __restrict__ w2p8,
                               signed char* __restrict__ w3p8,
                               unsigned short* __restrict__ wtf1b,
                               float* __restrict__ wtf2) {
    const int wi = blockIdx.y;
    const float* __restrict__ w = ta.w[wi];
    const int n = ta.n[wi];
    const double* sc = scr + wi * 4;
    const float delta = (float)(0.7 * sc[0] / (double)n);
    const int i0 = blockIdx.x * blockDim.x + threadIdx.x;
    const int stride = gridDim.x * blockDim.x;

    if (wi == 0) {
        for (int i = i0; i < n; i += stride) {       // n = 1728 = 64*27
            const int co = i / 27;
            const int kp = i % 27;                    // ci*9 + tap
            float v = w[i];
            signed char s = (fabsf(v) > delta) ? (v > 0.0f ? 1 : -1) : 0;
            w1b[co * 64 + kp] = s;                    // BL, k = kp
            w1b[4096 + co * 64 + 32 + kp] = s;        // BH, k = 32+kp
        }
    } else if (wi == 4) {
        const double c = sc[2];
        const float alpha = (float)(sc[1] / (c > 1.0 ? c : 1.0));
        for (int i = i0; i < n; i += stride) {
            float v = w[i];
            wtf2[i] = (fabsf(v) > delta) ? (v > 0.0f ? alpha : -alpha) : 0.0f;
        }
    } else if (wi == 1 || wi == 2) {
        const int CIc = (wi == 1) ? 64 : 128;
        const int COc = (wi == 1) ? 128 : 256;
        signed char* dst = (wi == 1) ? w2p8 : w3p8;
        for (int i = i0; i < n; i += stride) {
            const int co = i / (CIc * 9);
            const int r = i % (CIc * 9);
            const int ci = r / 9, tap = r % 9;
            float v = w[i];
            signed char s = (fabsf(v) > delta) ? (v > 0.0f ? 1 : -1) : 0;
            dst[(tap * COc + co) * CIc + ci] = s;
        }
    } else {  // wi == 3: fc1 signs, hi and lo slots
        for (int i = i0; i < n; i += stride) {
            const int j = i >> 12;
            const int k = i & 4095;
            const int c = k >> 4, px = k & 15;
            float v = w[i];
            unsigned short s = (fabsf(v) > delta) ? (v > 0.0f ? 0x3f80 : 0xbf80) : 0;
            unsigned short* row = wtf1b + ((long)j << 13) + px * 512 + c;
            row[0] = s;
            row[256] = s;
        }
    }
}

// ---------------------------------------------------------------------------
// conv1 (R12): i8 MFMA, no K-loop. Block = 1 image; M = 1024 pre-pool px
// (m = pp*4+sub pool swizzle), N = 64 co, K = 64 (ql at k<32, qh at k>=32;
// 27 valid (ci,tap) per half, rest zero-padded in B).
// LDS: quantized padded image, 2 planes of 3*34*34 bytes.
// accL = mfma(A, BL), accH = mfma(A, BH); sum = 256*accH + accL exact.
// ---------------------------------------------------------------------------
__global__ __launch_bounds__(256) void conv1_i8(
        const float* __restrict__ x,
        const signed char* __restrict__ w1b,   // [2][64 co][64 k]
        const float* __restrict__ bias,
        const double* __restrict__ scr,        // w1 stats {sum, msum, count}
        const int* __restrict__ amax_x,
        int* __restrict__ amax_out,
        float* __restrict__ y) {
    constexpr int PL = 3472;                   // plane stride bytes (>= 3*1156)
    __shared__ __align__(16) char X[2 * PL];
    __shared__ float redm[4];

    const int b = blockIdx.x;
    const int tid = threadIdx.x;
    const float S = 32512.0f / fmaxf(__int_as_float(*amax_x), 1e-30f);

    // zero both planes (2*3472/16 = 434 int4)
    for (int i = tid; i < 2 * PL / 16; i += 256)
        ((int4*)X)[i] = make_int4(0, 0, 0, 0);
    __syncthreads();

    // stage + quantize interior: 768 float4 per image
    for (int i = tid; i < 768; i += 256) {
        const float4 v = ((const float4*)(x + (long)b * 3072))[i];
        const int e = i * 4;
        const int ci = e >> 10;
        const int rem = e & 1023;
        const int h = rem >> 5, w = rem & 31;
        const int base = ci * 1156 + (h + 1) * 34 + (w + 1);
        const float f[4] = {v.x, v.y, v.z, v.w};
        #pragma unroll
        for (int j = 0; j < 4; j++) {
            const int q = __float2int_rn(f[j] * S);
            const int ql = (q << 24) >> 24;           // sign-extended low byte
            const int qh = (q - ql) >> 8;             // exact: q = qh*256 + ql
            X[base + j] = (char)ql;
            X[PL + base + j] = (char)qh;
        }
    }
    __syncthreads();

    const int lane = tid & 63;
    const int wid = tid >> 6;
    const int lm = lane & 15;
    const int kg = lane >> 4;

    // per-lane k constants: k = kg*16 + j; plane = (kg>=2) qh; kp = (kg&1)*16+j
    const int poff = (kg >= 2) ? PL : 0;
    int cst[16];
    #pragma unroll
    for (int j = 0; j < 16; j++) {
        const int kp = (kg & 1) * 16 + j;
        cst[j] = (kp < 27)
                     ? ((kp / 9) * 1156 + ((kp % 9) / 3) * 34 + (kp % 9) % 3)
                     : 0;                              // B=0 there; any byte ok
    }

    // B fragments: BL/BH x 4 n-tiles (b128 from L2-resident 8 KB)
    i32x4 BL[4], BH[4];
    #pragma unroll
    for (int nt = 0; nt < 4; nt++) {
        const int co = nt * 16 + lm;
        BL[nt] = *(const i32x4*)(w1b + (long)co * 64 + kg * 16);
        BH[nt] = *(const i32x4*)(w1b + 4096 + (long)co * 64 + kg * 16);
    }

    const double c2 = scr[2];
    const float alpha = (float)(scr[1] / (c2 > 1.0 ? c2 : 1.0));
    const float dq = alpha / S;
    float tmax = 0.f;
    float* yb = y + (long)b * 256 * 64;

    for (int tt = 0; tt < 16; ++tt) {
        const int t = wid * 16 + tt;
        // A-operand role: this lane supplies row m = t*16 + lm
        const int pp = t * 4 + (lm >> 2);
        const int sub = lm & 3;
        const int h = 2 * (pp >> 4) + (sub >> 1);
        const int w = 2 * (pp & 15) + (sub & 1);
        const int base = poff + h * 34 + w;            // raw[r] holds x[r-1]
        unsigned d[4] = {0u, 0u, 0u, 0u};
        #pragma unroll
        for (int j = 0; j < 16; j++) {
            const unsigned byte = (unsigned char)X[base + cst[j]];
            d[j >> 2] |= byte << ((j & 3) * 8);
        }
        i32x4 Af;
        Af[0] = (int)d[0]; Af[1] = (int)d[1];
        Af[2] = (int)d[2]; Af[3] = (int)d[3];

        // C/D role: lane holds rows kg*4+r, col lm -> pooled px t*4+kg
        const int opp = t * 4 + kg;
        float* yr = yb + (long)opp * 64;
        #pragma unroll
        for (int nt = 0; nt < 4; nt++) {
            i32x4 aL = 0, aH = 0;
            aL = __builtin_amdgcn_mfma_i32_16x16x64_i8(Af, BL[nt], aL, 0, 0, 0);
            aH = __builtin_amdgcn_mfma_i32_16x16x64_i8(Af, BH[nt], aH, 0, 0, 0);
            const int s0 = aH[0] * 256 + aL[0];
            const int s1 = aH[1] * 256 + aL[1];
            const int s2 = aH[2] * 256 + aL[2];
            const int s3 = aH[3] * 256 + aL[3];
            int sm = s0 > s1 ? s0 : s1;
            const int sn = s2 > s3 ? s2 : s3;
            sm = sm > sn ? sm : sn;
            const int co = nt * 16 + lm;
            const float o = fmaxf(dq * (float)sm + bias[co], 0.f);
            tmax = fmaxf(tmax, o);
            yr[co] = o;
        }
    }

    #pragma unroll
    for (int off = 32; off > 0; off >>= 1)
        tmax = fmaxf(tmax, __shfl_down(tmax, off, 64));
    if (lane == 0) redm[wid] = tmax;
    __syncthreads();
    if (tid == 0) {
        float m = fmaxf(fmaxf(redm[0], redm[1]), fmaxf(redm[2], redm[3]));
        atomicMax(amax_out, __float_as_int(m));
    }
}

// ---------------------------------------------------------------------------
// int8 MFMA conv (unchanged from R11). WM x WN wave grid, MT=NT=4.
// ---------------------------------------------------------------------------
template <int CI, int HI, int CO, int HB, int WM, int WN, bool INF32>
__global__ __launch_bounds__(256) void conv_i8(
        const void* __restrict__ xin,
        const signed char* __restrict__ wp,     // [9][CO][CI] int8 signs
        const float* __restrict__ bias,
        const double* __restrict__ scr,         // layer {_, msum, count}
        const int* __restrict__ amax_in,
        int* __restrict__ amax_out,             // nullptr if unused
        unsigned short* __restrict__ yout) {
    constexpr int CH8 = CI / 64;
    constexpr int NITER = 9 * CH8;
    constexpr int HR = HI / HB;
    constexpr int ROWS = HR + 2;
    constexpr int COLS = HI + 2;
    constexpr int NPIX = ROWS * COLS;
    constexpr int PSTR = NPIX * 64 + 32;    // bytes per g-plane
    constexpr int PO = HI / 2;
    constexpr int POR = HR / 2;
    constexpr int MT = 4, NT = 4;
    constexpr int NST = ROWS * HI * (CI / 8) / 256;
    static_assert(WM * WN == 4, "4 waves");
    static_assert(WM * 64 == HR * HI, "M covers slab pixels");
    static_assert(WN * 64 == CO, "N covers all co");
    static_assert(NST * 256 == ROWS * HI * (CI / 8), "exact staging trips");

    __shared__ __align__(16) char X[2 * CH8 * PSTR];
    __shared__ float redm[4];

    const int bimg = blockIdx.x / HB;
    const int hb = blockIdx.x % HB;
    const int tid = threadIdx.x;

    const float S = 32512.0f / fmaxf(__int_as_float(*amax_in), 1e-30f);

    // halo zero (borders only; disjoint from interior staging)
    constexpr int HALO = 2 * COLS + 2 * (ROWS - 2);
    for (int i = tid; i < HALO * 2 * CH8 * 4; i += 256) {
        const int u = i & 3;
        const int t = i >> 2;
        const int g = t % (2 * CH8);
        const int hp = t / (2 * CH8);
        int p;
        if (hp < COLS) p = hp;
        else if (hp < 2 * COLS) p = (ROWS - 1) * COLS + (hp - COLS);
        else {
            const int e = hp - 2 * COLS;
            p = (1 + (e >> 1)) * COLS + ((e & 1) ? (COLS - 1) : 0);
        }
        *(int4*)&X[g * PSTR + p * 64 + u * 16] = make_int4(0, 0, 0, 0);
    }

    // ---- staging phase 1: batch all global loads ----
    uint4 va[NST], vb[NST];
    bool val[NST];
    int pidx[NST], cbase[NST];
    #pragma unroll
    for (int s2 = 0; s2 < NST; s2++) {
        const int i = tid + s2 * 256;
        const int q8 = i % (CI / 8);
        const int t = i / (CI / 8);
        const int c = t % HI;
        const int r = t / HI;
        const int h = hb * HR + r - 1;
        val[s2] = (unsigned)h < (unsigned)HI;
        pidx[s2] = r * COLS + c + 1;
        cbase[s2] = q8 * 8;
        if (val[s2]) {
            if (INF32) {
                const float* pxr = (const float*)xin +
                    ((long)(bimg * HI + h) * HI + c) * CI + q8 * 8;
                va[s2] = *(const uint4*)(pxr);
                vb[s2] = *(const uint4*)(pxr + 4);
            } else {
                const unsigned short* pxr = (const unsigned short*)xin +
                    ((long)(bimg * HI + h) * HI + c) * (2 * CI);
                va[s2] = *(const uint4*)(pxr + q8 * 8);
                vb[s2] = *(const uint4*)(pxr + CI + q8 * 8);
            }
        }
    }
    // ---- staging phase 2: quantize + LDS store ----
    #pragma unroll
    for (int s2 = 0; s2 < NST; s2++) {
        if (!val[s2]) continue;
        float f[8];
        if (INF32) {
            const float* fa = (const float*)&va[s2];
            const float* fb = (const float*)&vb[s2];
            #pragma unroll
            for (int j = 0; j < 4; j++) { f[j] = fa[j]; f[4 + j] = fb[j]; }
        } else {
            const unsigned* hw = (const unsigned*)&va[s2];
            const unsigned* lw = (const unsigned*)&vb[s2];
            #pragma unroll
            for (int j = 0; j < 8; j++) {
                const unsigned hu = (j & 1) ? (hw[j >> 1] >> 16)
                                            : (hw[j >> 1] & 0xffffu);
                const unsigned lu = (j & 1) ? (lw[j >> 1] >> 16)
                                            : (lw[j >> 1] & 0xffffu);
                f[j] = __uint_as_float(hu << 16) + __uint_as_float(lu << 16);
            }
        }
        unsigned pl0 = 0, pl1 = 0, ph0 = 0, ph1 = 0;
        #pragma unroll
        for (int j = 0; j < 8; j++) {
            const int qi = (int)(f[j] * S + 0.5f);    // inputs >= 0 (post-relu)
            const int ql = (qi << 24) >> 24;
            const int qh = (qi - ql) >> 8;
            const int sh = (j & 3) * 8;
            if (j < 4) {
                pl0 |= (unsigned)(ql & 255) << sh;
                ph0 |= (unsigned)(qh & 255) << sh;
            } else {
                pl1 |= (unsigned)(ql & 255) << sh;
                ph1 |= (unsigned)(qh & 255) << sh;
            }
        }
        const int p = pidx[s2];
        const int ch = cbase[s2] >> 6;
        const int cc = cbase[s2] & 63;
        const int slot = ((cc >> 4) + (p >> 1)) & 3;
        const int base = p * 64 + slot * 16 + (cc & 15);
        *(uint2*)&X[ch * PSTR + base] = make_uint2(pl0, pl1);
        *(uint2*)&X[(CH8 + ch) * PSTR + base] = make_uint2(ph0, ph1);
    }
    __syncthreads();

    const int lane = tid & 63;
    const int wid = tid >> 6;
    const int wm = (WM == 1) ? 0 : (wid >> 1);
    const int wn = (WM == 1) ? wid : (wid & 1);
    const int lm = lane & 15;
    const int kg = lane >> 4;

    int pb[MT];
    #pragma unroll
    for (int mt = 0; mt < MT; mt++) {
        const int m = (wm * MT + mt) * 16 + lm;
        const int pp = m >> 2, sub = m & 3;
        const int lph = pp / PO, lpw = pp % PO;
        const int h = 2 * lph + (sub >> 1);
        const int w = 2 * lpw + (sub & 1);
        pb[mt] = h * COLS + w;
    }
    const signed char* bp[NT];
    #pragma unroll
    for (int nt = 0; nt < NT; nt++) {
        const int co = (wn * NT + nt) * 16 + lm;
        bp[nt] = wp + (long)co * CI + kg * 16;
    }

    i32x4 accL[MT][NT], accH[MT][NT];
    #pragma unroll
    for (int mt = 0; mt < MT; mt++)
        #pragma unroll
        for (int nt = 0; nt < NT; nt++) { accL[mt][nt] = 0; accH[mt][nt] = 0; }

    i32x4 Bb[2][NT];
    #pragma unroll
    for (int nt = 0; nt < NT; nt++) Bb[0][nt] = *(const i32x4*)(bp[nt]);

    #pragma unroll 2
    for (int it = 0; it < NITER; ++it) {
        const int cur = it & 1, nxt = cur ^ 1;
        if (it + 1 < NITER) {
            const int it1 = it + 1;
            const int tap = it1 / CH8, ch1 = it1 % CH8;
            const int woff = tap * CO * CI + ch1 * 64;
            #pragma unroll
            for (int nt = 0; nt < NT; nt++)
                Bb[nxt][nt] = *(const i32x4*)(bp[nt] + woff);
        }
        const int tap = it / CH8, ch = it % CH8;
        const int dtap = (tap / 3) * COLS + (tap % 3);
        i32x4 Af0[MT], Af1[MT];
        #pragma unroll
        for (int mt = 0; mt < MT; mt++) {
            const int p = pb[mt] + dtap;
            const int ao = p * 64 + (((kg + (p >> 1)) & 3) << 4);
            Af0[mt] = *(const i32x4*)&X[ch * PSTR + ao];
            Af1[mt] = *(const i32x4*)&X[(CH8 + ch) * PSTR + ao];
        }
        #pragma unroll
        for (int mt = 0; mt < MT; mt++)
            #pragma unroll
            for (int nt = 0; nt < NT; nt++)
                accL[mt][nt] = __builtin_amdgcn_mfma_i32_16x16x64_i8(
                    Af0[mt], Bb[cur][nt], accL[mt][nt], 0, 0, 0);
        #pragma unroll
        for (int mt = 0; mt < MT; mt++)
            #pragma unroll
            for (int nt = 0; nt < NT; nt++)
                accH[mt][nt] = __builtin_amdgcn_mfma_i32_16x16x64_i8(
                    Af1[mt], Bb[cur][nt], accH[mt][nt], 0, 0, 0);
    }

    // epilogue: sum = 256*accH + accL (exact i32); pool in int; dq + bias + relu
    const double c2 = scr[2];
    const float alpha = (float)(scr[1] / (c2 > 1.0 ? c2 : 1.0));
    const float dq = alpha / S;
    float tmax = 0.f;
    #pragma unroll
    for (int mt = 0; mt < MT; mt++) {
        const int pp = (wm * MT + mt) * 4 + kg;
        const int lph = pp / PO, lpw = pp % PO;
        const int gpp = (hb * POR + lph) * PO + lpw;
        unsigned short* yr = yout + ((long)bimg * (PO * PO) + gpp) * (2 * CO);
        #pragma unroll
        for (int nt = 0; nt < NT; nt++) {
            const int co = (wn * NT + nt) * 16 + lm;
            const i32x4 aL = accL[mt][nt], aH = accH[mt][nt];
            int s0 = aH[0] * 256 + aL[0];
            int s1 = aH[1] * 256 + aL[1];
            int s2 = aH[2] * 256 + aL[2];
            int s3 = aH[3] * 256 + aL[3];
            int sm = s0 > s1 ? s0 : s1;
            int sn = s2 > s3 ? s2 : s3;
            sm = sm > sn ? sm : sn;
            float o = fmaxf(dq * (float)sm + bias[co], 0.f);
            tmax = fmaxf(tmax, o);
            unsigned short hi = f2bf(o);
            unsigned short lo = f2bf(o - bf2f(hi));
            yr[co] = hi;
            yr[CO + co] = lo;
        }
    }
    if (amax_out) {
        #pragma unroll
        for (int off = 32; off > 0; off >>= 1)
            tmax = fmaxf(tmax, __shfl_down(tmax, off, 64));
        if (lane == 0) redm[wid] = tmax;
        __syncthreads();
        if (tid == 0) {
            float m = fmaxf(fmaxf(redm[0], redm[1]), fmaxf(redm[2], redm[3]));
            atomicMax(amax_out, __float_as_int(m));
        }
    }
}

// ---------------------------------------------------------------------------
// fc1 MFMA (bf16): K=8192 hi/lo slots, split-K, reg-pipelined.
// ---------------------------------------------------------------------------
template <int S>
__global__ __launch_bounds__(256) void fc1_mfma(
        const unsigned short* __restrict__ A,
        const unsigned short* __restrict__ Bw,
        float* __restrict__ parts) {
    constexpr int KCH = 8192 / S;
    constexpr int NSTEP = KCH / 32;
    const int m0 = blockIdx.x * 128;
    const int n0 = blockIdx.y * 128;
    const int s = blockIdx.z;
    const int tid = threadIdx.x;
    const int lane = tid & 63, wid = tid >> 6;
    const int wm = wid >> 1, wn = wid & 1;
    const int lm = lane & 15, kg = lane >> 4;

    const long k0 = (long)s * KCH + kg * 8;
    const unsigned short* ap[4];
    const unsigned short* bp[4];
    #pragma unroll
    for (int t = 0; t < 4; t++) {
        ap[t] = A + (long)(m0 + wm * 64 + t * 16 + lm) * 8192 + k0;
        bp[t] = Bw + (long)(n0 + wn * 64 + t * 16 + lm) * 8192 + k0;
    }

    f32x4 acc[4][4] = {};
    short8 Ab[2][4], Bb[2][4];
    #pragma unroll
    for (int t = 0; t < 4; t++) {
        Ab[0][t] = *(const short8*)(ap[t]);
        Bb[0][t] = *(const short8*)(bp[t]);
    }

    #pragma unroll 2
    for (int st = 0; st < NSTEP; ++st) {
        const int cur = st & 1, nxt = cur ^ 1;
        if (st + 1 < NSTEP) {
            const int off = (st + 1) * 32;
            #pragma unroll
            for (int t = 0; t < 4; t++) {
                Ab[nxt][t] = *(const short8*)(ap[t] + off);
                Bb[nxt][t] = *(const short8*)(bp[t] + off);
            }
        }
        #pragma unroll
        for (int mt = 0; mt < 4; mt++)
            #pragma unroll
            for (int nt = 0; nt < 4; nt++)
                acc[mt][nt] = __builtin_amdgcn_mfma_f32_16x16x32_bf16(
                    Ab[cur][mt], Bb[cur][nt], acc[mt][nt], 0, 0, 0);
    }

    #pragma unroll
    for (int mt = 0; mt < 4; mt++) {
        #pragma unroll
        for (int r = 0; r < 4; r++) {
            const int b = m0 + wm * 64 + mt * 16 + kg * 4 + r;
            #pragma unroll
            for (int nt = 0; nt < 4; nt++) {
                const int j = n0 + wn * 64 + nt * 16 + lm;
                parts[((long)s * 1024 + b) * 256 + j] = acc[mt][nt][r];
            }
        }
    }
}

template <int S>
__global__ void fc1_reduce(const float* __restrict__ parts,
                           const double* __restrict__ scr,
                           const float* __restrict__ bias,
                           float* __restrict__ f1) {
    const int idx = blockIdx.x * blockDim.x + threadIdx.x;  // < 262144
    const int j = idx & 255;
    float s = 0.f;
    #pragma unroll
    for (int p = 0; p < S; p++) s += parts[(long)p * 262144 + idx];
    const double c2 = scr[2];
    const float alpha = (float)(scr[1] / (c2 > 1.0 ? c2 : 1.0));
    f1[idx] = fmaxf(alpha * s + bias[j], 0.f);
}

__global__ void fc2_kernel(const float* __restrict__ a,
                           const float* __restrict__ wt,
                           const float* __restrict__ bias,
                           float* __restrict__ out, int B) {
    const int idx = blockIdx.x * blockDim.x + threadIdx.x;
    if (idx >= B * 10) return;
    const int k = idx % 10;
    const int b = idx / 10;
    const float* ar = a + (long)b * 256;
    const float* wr = wt + (long)k * 256;
    float acc = 0.f;
    #pragma unroll 4
    for (int i = 0; i < 256; i++) acc += ar[i] * wr[i];
    out[idx] = acc + bias[k];
}

extern "C" void kernel_launch(void* const* d_in, const int* in_sizes, int n_in,
                              void* d_out, int out_size, void* d_ws, size_t ws_size,
                              hipStream_t stream) {
    const float* x   = (const float*)d_in[0];
    const float* w1  = (const float*)d_in[1];
    const float* b1  = (const float*)d_in[2];
    const float* w2  = (const float*)d_in[3];
    const float* b2  = (const float*)d_in[4];
    const float* w3  = (const float*)d_in[5];
    const float* b3  = (const float*)d_in[6];
    const float* wf1 = (const float*)d_in[7];
    const float* bf1 = (const float*)d_in[8];
    const float* wf2 = (const float*)d_in[9];
    const float* bf2 = (const float*)d_in[10];
    float* out = (float*)d_out;
    float* ws = (float*)d_ws;

    const int B = 1024;

    signed char*    w1b   = (signed char*)(ws + WS_W1B);
    signed char*    w2p8  = (signed char*)(ws + WS_W2P);
    signed char*    w3p8  = (signed char*)(ws + WS_W3P);
    unsigned short* wtf1b = (unsigned short*)(ws + WS_WTF1);
    float*          wtf2  = ws + WS_WTF2;
    float*          a1f   = ws + WS_A1;
    unsigned short* a2p   = (unsigned short*)(ws + WS_A2);
    unsigned short* a3p   = (unsigned short*)(ws + WS_A3);
    float*          f1    = ws + WS_F1;
    double*         scr   = (double*)(ws + WS_SCR);
    int*            iscr  = (int*)(scr + 20);
    int*            amaxx = iscr;           // amax(x)
    int*            amax1 = iscr + 1;       // amax(a1)
    int*            amax2 = iscr + 2;       // amax(a2)
    float*          parts = ws + WS_A1;     // alias: a1 dead after conv2

    hipMemsetAsync(scr, 0, 22 * sizeof(double), stream);
    hipMemsetAsync(w1b, 0, 8192, stream);   // BL/BH zero padding

    TernArgs ta;
    ta.w[0] = w1;  ta.n[0] = 64 * 27;
    ta.w[1] = w2;  ta.n[1] = 128 * 64 * 9;
    ta.w[2] = w3;  ta.n[2] = 256 * 128 * 9;
    ta.w[3] = wf1; ta.n[3] = 256 * 4096;
    ta.w[4] = wf2; ta.n[4] = 10 * 256;
    ta.w[5] = x;   ta.n[5] = 1024 * 3 * 32 * 32;   // amax(x)

    hipLaunchKernelGGL(tern_stats1, dim3(128, 6), dim3(256), 0, stream, ta, scr);
    hipLaunchKernelGGL(tern_stats2, dim3(128, 5), dim3(256), 0, stream, ta, scr);
    hipLaunchKernelGGL(tern_write_all, dim3(128, 5), dim3(256), 0, stream,
                       ta, scr, w1b, w2p8, w3p8, wtf1b, wtf2);

    // conv1: i8 MFMA, 1 block per image -> a1 fp32 rows + amax1
    hipLaunchKernelGGL(conv1_i8, dim3(B), dim3(256), 0, stream,
                       x, w1b, b1, scr + 0, amaxx, amax1, a1f);

    // conv2: CI=64, HI=16, CO=128, HB=2, WM=2, WN=2, fp32 input -> 2048 blocks
    hipLaunchKernelGGL((conv_i8<64, 16, 128, 2, 2, 2, true>), dim3(B * 2),
                       dim3(256), 0, stream, a1f, w2p8, b2, scr + 4, amax1,
                       amax2, a2p);

    // conv3: CI=128, HI=8, CO=256, HB=1, WM=1, WN=4 (all co) -> 1024 blocks
    hipLaunchKernelGGL((conv_i8<128, 8, 256, 1, 1, 4, false>), dim3(B),
                       dim3(256), 0, stream, a2p, w3p8, b3, scr + 8, amax2,
                       (int*)nullptr, a3p);

    // fc1: MFMA split-K + reduce(alpha+bias+relu)
    hipLaunchKernelGGL((fc1_mfma<FC1_S>), dim3(8, 2, FC1_S), dim3(256), 0, stream,
                       a3p, wtf1b, parts);
    hipLaunchKernelGGL((fc1_reduce<FC1_S>), dim3(1024), dim3(256), 0, stream,
                       parts, scr + 12, bf1, f1);

    // fc2
    hipLaunchKernelGGL(fc2_kernel, dim3((B * 10 + 255) / 256), dim3(256), 0,
                       stream, f1, wtf2, bf2, out, B);
}